// Round 7
// baseline (882.208 us; speedup 1.0000x reference)
//
#include <hip/hip_runtime.h>
#include <hip/hip_cooperative_groups.h>
#include <math.h>

namespace cg = cooperative_groups;

// HGNNPBlock: per-sample kNN hypergraph (k=30) + 2x (theta -> bn -> v2v mean).
// B=8, L=56*56=3136, C=64, hid=32.
//
// R20 = R19 (373.5us) + cooperative mega-kernel for the post-rescore chain:
//   k_post = {scan, fill, e2v_t2, v2e64, e2v64} in one cooperative launch
//   (1024 blocks x 256, grid.sync between phases, bodies verbatim ports).
//   Purpose: (1) remove 4 kernel boundaries (launch gap + drain each);
//   (2) VISIBILITY -- back-half cost (252us, invisible behind 5x k_sweep
//   rows in top-5) becomes one measurable dispatch. __launch_bounds__(256,4)
//   caps VGPR at 128 -> >=4 blocks/CU co-resident >= 1024 blocks. LDS 8KB.
// k_splitth / k_sweep / k_rescore unchanged from R19.

namespace {

constexpr int cB = 8;
constexpr int cL = 3136;
constexpr int cC = 64;
constexpr int cH = 32;
constexpr int cK = 30;
constexpr int NV = cB * cL;   // 25088
constexpr int QD = 10;        // per-lane queue depth
constexpr float BN_SC = 0.99999500003749964f;  // 1/sqrt(1+1e-5) in fp32

typedef __bf16 bf16x8 __attribute__((ext_vector_type(8)));
typedef float floatx4 __attribute__((ext_vector_type(4)));

union BU {
  __bf16 b[2];
  unsigned u;
};

__device__ inline unsigned umin2(unsigned a, unsigned b) { return a < b ? a : b; }
__device__ inline unsigned umax2(unsigned a, unsigned b) { return a > b ? a : b; }
__device__ inline unsigned umin3(unsigned a, unsigned b, unsigned c) {
  return umin2(umin2(a, b), c);  // compiler fuses to v_min3_u32
}
__device__ inline float bf16lo(unsigned u) { return __uint_as_float(u << 16); }
__device__ inline float bf16hi(unsigned u) {
  return __uint_as_float(u & 0xFFFF0000u);
}

// sort a bitonic 64-sequence (one value per lane) ascending, shfl-only
__device__ inline unsigned bclean64(unsigned v, int ln) {
#pragma unroll
  for (int off = 32; off; off >>= 1) {
    unsigned p = (unsigned)__shfl_xor((int)v, off);
    v = (ln & off) ? umax2(v, p) : umin2(v, p);
  }
  return v;
}

// ------- K0: split + |x|^2 + theta1 + bn, fused (per-vertex maps over x) ---
// grid 3136 x 256: block = 8 vertices x 32 features. x staged in LDS once.
__global__ __launch_bounds__(256) void k_splitth(
    const float* __restrict__ x, const float* __restrict__ w1,
    const float* __restrict__ b1, const float* __restrict__ g1,
    const float* __restrict__ be1, ushort* __restrict__ xhi,
    ushort* __restrict__ xlo, float* __restrict__ sqf,
    int* __restrict__ cnt, int* __restrict__ cur, __bf16* __restrict__ h1) {
  __shared__ float w1s[cC * cH];  // 8 KB
  __shared__ float xs[8 * 64];    // 2 KB
  const int t = threadIdx.x;
  const int v0 = blockIdx.x * 8;
  for (int n = t; n < cC * cH; n += 256) w1s[n] = w1[n];
  {
    float2 xv = reinterpret_cast<const float2*>(x + (size_t)v0 * 64)[t];
    xs[2 * t] = xv.x;
    xs[2 * t + 1] = xv.y;
    BU hh, ll;
    hh.b[0] = (__bf16)xv.x;
    hh.b[1] = (__bf16)xv.y;
    ll.b[0] = (__bf16)(xv.x - (float)hh.b[0]);
    ll.b[1] = (__bf16)(xv.y - (float)hh.b[1]);
    reinterpret_cast<unsigned*>(xhi)[(size_t)v0 * 32 + t] = hh.u;
    reinterpret_cast<unsigned*>(xlo)[(size_t)v0 * 32 + t] = ll.u;
    float ss = xv.x * xv.x + xv.y * xv.y;  // row r = t>>5 spans lanes r*32..+31
#pragma unroll
    for (int off = 1; off < 32; off <<= 1) ss += __shfl_xor(ss, off);
    if ((t & 31) == 0) sqf[v0 + (t >> 5)] = ss * 1024.f + 262144.f;  // q20
  }
  if (t < 8) {
    cnt[v0 + t] = 0;
    cur[v0 + t] = 0;
  }
  __syncthreads();
  const int r = t >> 5, f = t & 31;
  float s = 0.f;
#pragma unroll
  for (int k = 0; k < cC; ++k) s = fmaf(xs[r * 64 + k], w1s[k * cH + f], s);
  h1[(size_t)(v0 + r) * cH + f] =
      (__bf16)((s + b1[f]) * (g1[f] * BN_SC) + be1[f]);
}

// ------- K1: fused gram sweep + branchless top-10 -> per-half top-40 ------
// grid (98, 2, 8): 32-row strip x col-half x sample. block 128 (2 waves);
// wave w rows w*16..w*16+15; lane (tx,qd) rows qd*4+e, cols f*16+tx (f<2).
__global__ __launch_bounds__(128, 4) void k_sweep(
    const ushort* __restrict__ xhi, const ushort* __restrict__ xlo,
    const float* __restrict__ sqf, unsigned* __restrict__ candq) {
  const int ib = blockIdx.x, qt = blockIdx.y, b = blockIdx.z;
  const int r0 = ib * 32;
  const int jb0 = qt * 1568;
  const int ntile = 49;  // 32-col tiles; 2 * 49*32 = 3136 (exact halves)
  const size_t bbase = (size_t)b * cL;

  __shared__ ushort aHi[32 * 72], aLo[32 * 72];  // stride 72: conflict-free
  __shared__ ushort bHi[32 * 72], bLo[32 * 72];
  __shared__ float sqJs[32];

  const int t  = threadIdx.x;  // 0..127
  const int ln = t & 63;
  const int w  = t >> 6;       // wave -> 16-row group
  const int tx = ln & 15;
  const int qd = ln >> 4;

#pragma unroll
  for (int it = 0; it < 2; ++it) {  // stage A strip (32 rows x 8 uint4 chunks)
    int idx = t + 128 * it;
    int r = idx >> 3, blk = idx & 7;
    *reinterpret_cast<uint4*>(&aHi[r * 72 + blk * 8]) =
        *reinterpret_cast<const uint4*>(&xhi[(bbase + r0 + r) * 64 + blk * 8]);
    *reinterpret_cast<uint4*>(&aLo[r * 72 + blk * 8]) =
        *reinterpret_cast<const uint4*>(&xlo[(bbase + r0 + r) * 64 + blk * 8]);
  }
  __syncthreads();

  bf16x8 aH[2], aL[2];
#pragma unroll
  for (int kk = 0; kk < 2; ++kk) {
    aH[kk] = *reinterpret_cast<const bf16x8*>(
        &aHi[(w * 16 + tx) * 72 + kk * 32 + qd * 8]);
    aL[kk] = *reinterpret_cast<const bf16x8*>(
        &aLo[(w * 16 + tx) * 72 + kk * 32 + qd * 8]);
  }

  unsigned q[4][QD];  // per-row sorted top-QD (ascending), packed q20|col12
#pragma unroll
  for (int e = 0; e < 4; ++e)
#pragma unroll
    for (int k = 0; k < QD; ++k) q[e][k] = 0xFFFFFFFFu;

  // register prefetch of B tiles (async-STAGE split)
  const int pr  = (t + 0)   >> 3, pblk  = (t + 0)   & 7;   // it=0 slot
  const int pr1 = (t + 128) >> 3, pblk1 = (t + 128) & 7;   // it=1 slot
  uint4 pH0, pH1, pL0, pL1;
  float pS = 0.f;
  {
    const int jb = jb0;
    pH0 = *reinterpret_cast<const uint4*>(&xhi[(bbase + jb + pr) * 64 + pblk * 8]);
    pL0 = *reinterpret_cast<const uint4*>(&xlo[(bbase + jb + pr) * 64 + pblk * 8]);
    pH1 = *reinterpret_cast<const uint4*>(&xhi[(bbase + jb + pr1) * 64 + pblk1 * 8]);
    pL1 = *reinterpret_cast<const uint4*>(&xlo[(bbase + jb + pr1) * 64 + pblk1 * 8]);
    if (t < 32) pS = sqf[bbase + jb + t];
  }

  for (int st = 0; st < ntile; ++st) {
    __syncthreads();  // prev compute done -> LDS writable; drains prefetch vmcnt
    *reinterpret_cast<uint4*>(&bHi[pr * 72 + pblk * 8])   = pH0;
    *reinterpret_cast<uint4*>(&bLo[pr * 72 + pblk * 8])   = pL0;
    *reinterpret_cast<uint4*>(&bHi[pr1 * 72 + pblk1 * 8]) = pH1;
    *reinterpret_cast<uint4*>(&bLo[pr1 * 72 + pblk1 * 8]) = pL1;
    if (t < 32) sqJs[t] = pS;
    __syncthreads();  // tile st ready

    // issue loads for tile st+1 NOW (after the barrier so its vmcnt(0) drain
    // doesn't eat them); they retire during the compute below.
    if (st + 1 < ntile) {
      const int jb = jb0 + (st + 1) * 32;
      pH0 = *reinterpret_cast<const uint4*>(&xhi[(bbase + jb + pr) * 64 + pblk * 8]);
      pL0 = *reinterpret_cast<const uint4*>(&xlo[(bbase + jb + pr) * 64 + pblk * 8]);
      pH1 = *reinterpret_cast<const uint4*>(&xhi[(bbase + jb + pr1) * 64 + pblk1 * 8]);
      pL1 = *reinterpret_cast<const uint4*>(&xlo[(bbase + jb + pr1) * 64 + pblk1 * 8]);
      if (t < 32) pS = sqf[bbase + jb + t];
    }
    __builtin_amdgcn_sched_barrier(0);  // keep prefetch issue above compute

    unsigned pk[2][4];  // packed candidates per f per e
#pragma unroll
    for (int f = 0; f < 2; ++f) {
      const int bro = (f * 16 + tx) * 72 + qd * 8;
      bf16x8 bh0 = *reinterpret_cast<const bf16x8*>(&bHi[bro]);
      bf16x8 bh1 = *reinterpret_cast<const bf16x8*>(&bHi[bro + 32]);
      bf16x8 bl0 = *reinterpret_cast<const bf16x8*>(&bLo[bro]);
      bf16x8 bl1 = *reinterpret_cast<const bf16x8*>(&bLo[bro + 32]);
      floatx4 acc = {0.f, 0.f, 0.f, 0.f};
      acc = __builtin_amdgcn_mfma_f32_16x16x32_bf16(aH[0], bh0, acc, 0, 0, 0);
      acc = __builtin_amdgcn_mfma_f32_16x16x32_bf16(aH[1], bh1, acc, 0, 0, 0);
      acc = __builtin_amdgcn_mfma_f32_16x16x32_bf16(aH[0], bl0, acc, 0, 0, 0);
      acc = __builtin_amdgcn_mfma_f32_16x16x32_bf16(aH[1], bl1, acc, 0, 0, 0);
      acc = __builtin_amdgcn_mfma_f32_16x16x32_bf16(aL[0], bh0, acc, 0, 0, 0);
      acc = __builtin_amdgcn_mfma_f32_16x16x32_bf16(aL[1], bh1, acc, 0, 0, 0);
      const float sjs = sqJs[f * 16 + tx];
      const unsigned col = (unsigned)(jb0 + st * 32 + f * 16 + tx);
#pragma unroll
      for (int e = 0; e < 4; ++e) {
        // q20 quantized d2 (|xi|^2 dropped: row-constant, ranks unaffected)
        float qf = fmaf(acc[e], -2048.f, sjs);
        qf = fminf(fmaxf(qf, 0.f), 1048575.f);  // clamp to 20 bits
        pk[f][e] = ((unsigned)qf << 12) | col;
      }
    }

    // branchless pair-insert: keep smallest QD of q U {a0,a1}, a0<=a1.
    // new_q[i] = min3(q[i], max(q[i-1],a0), max(q[i-2],a1)), descending i.
#pragma unroll
    for (int e = 0; e < 4; ++e) {
      unsigned a0 = umin2(pk[0][e], pk[1][e]);
      unsigned a1 = umax2(pk[0][e], pk[1][e]);
#pragma unroll
      for (int i = QD - 1; i >= 2; --i)
        q[e][i] = umin3(q[e][i], umax2(q[e][i - 1], a0),
                        umax2(q[e][i - 2], a1));
      q[e][1] = umin3(q[e][1], umax2(q[e][0], a0), a1);
      q[e][0] = umin3(q[e][0], a0, a1);
    }
  }

  // extraction: 40 wave-min pops per row; e-interleaved -> 4 independent
  // dependency chains in flight.
  unsigned* cr[4];
#pragma unroll
  for (int e = 0; e < 4; ++e)
    cr[e] = candq + (bbase + r0 + w * 16 + qd * 4 + e) * 80 + qt * 40;
  for (int it = 0; it < 40; ++it) {
    unsigned h0 = q[0][0], h1 = q[1][0], h2 = q[2][0], h3 = q[3][0];
    unsigned m0 = h0, m1 = h1, m2 = h2, m3 = h3;
#pragma unroll
    for (int off = 1; off < 16; off <<= 1) {
      m0 = umin2(m0, (unsigned)__shfl_xor((int)m0, off));
      m1 = umin2(m1, (unsigned)__shfl_xor((int)m1, off));
      m2 = umin2(m2, (unsigned)__shfl_xor((int)m2, off));
      m3 = umin2(m3, (unsigned)__shfl_xor((int)m3, off));
    }
    if (tx == 0) {
      cr[0][it] = m0;
      cr[1][it] = m1;
      cr[2][it] = m2;
      cr[3][it] = m3;
    }
    if (h0 == m0) {  // keys distinct (col in low bits) -> exactly one pop
#pragma unroll
      for (int k = 0; k < QD - 1; ++k) q[0][k] = q[0][k + 1];
      q[0][QD - 1] = 0xFFFFFFFFu;
    }
    if (h1 == m1) {
#pragma unroll
      for (int k = 0; k < QD - 1; ++k) q[1][k] = q[1][k + 1];
      q[1][QD - 1] = 0xFFFFFFFFu;
    }
    if (h2 == m2) {
#pragma unroll
      for (int k = 0; k < QD - 1; ++k) q[2][k] = q[2][k + 1];
      q[2][QD - 1] = 0xFFFFFFFFu;
    }
    if (h3 == m3) {
#pragma unroll
      for (int k = 0; k < QD - 1; ++k) q[3][k] = q[3][k + 1];
      q[3][QD - 1] = 0xFFFFFFFFu;
    }
  }
}

// ------- K2: merge 2 sorted lists + cond. fp64 re-rank + fused v2e32 ------
__global__ __launch_bounds__(256) void k_rescore(
    const float* __restrict__ x, const unsigned* __restrict__ candq,
    const __bf16* __restrict__ h1, int* __restrict__ nbr,
    int* __restrict__ cnt, __bf16* __restrict__ Y1) {
  const int w  = threadIdx.x >> 6;
  const int ln = threadIdx.x & 63;
  const size_t row = (size_t)blockIdx.x * 4 + w;
  const size_t bvert = row - (row % cL);  // b*cL

  const unsigned* cq = candq + row * 80;
  unsigned A = (ln < 40) ? cq[ln]      : 0xFFFFFFFFu;
  unsigned B = (ln < 40) ? cq[40 + ln] : 0xFFFFFFFFu;

  // split-min + bitonic clean: sorted lower-64 of the 2-list union
  unsigned g = umin2(A, (unsigned)__shfl((int)B, 63 - ln));
  g = bclean64(g, ln);  // sorted asc; lanes 0..39 = global top-40 (all real)

  const unsigned qv = g >> 12;  // 20-bit quantized distance
  const int col = min((int)(g & 0xFFFu), cL - 1);  // clamp: garbage-proof

  // quantized gap at the 29/30 boundary (sorted -> just neighbors)
  unsigned q29 = (unsigned)__shfl((int)qv, 29);
  unsigned q30 = (unsigned)__shfl((int)qv, 30);
  int myc = col;  // fast path: lane == rank already
  if (!(q30 > q29 + 6)) {  // wave-uniform branch
    // ambiguous boundary: exact fp64 re-rank of the 40 merged candidates
    float4 xi[16];
    const float4* xi4 = reinterpret_cast<const float4*>(x + row * 64);
#pragma unroll
    for (int c = 0; c < 16; ++c) xi[c] = xi4[c];
    double dv = 1e300;
    if (ln < 40) {
      const float4* xj4 =
          reinterpret_cast<const float4*>(x + (bvert + col) * 64);
      double ax = 0.0, ay = 0.0, az = 0.0, aw = 0.0;
#pragma unroll
      for (int c = 0; c < 16; ++c) {
        float4 xj = xj4[c];
        double d0 = (double)xi[c].x - (double)xj.x; ax = fma(d0, d0, ax);
        double d1 = (double)xi[c].y - (double)xj.y; ay = fma(d1, d1, ay);
        double d2 = (double)xi[c].z - (double)xj.z; az = fma(d2, d2, az);
        double d3 = (double)xi[c].w - (double)xj.w; aw = fma(d3, d3, aw);
      }
      dv = (ax + ay) + (az + aw);
    }
    int r2 = 0;
    for (int j = 0; j < 40; ++j) {
      double od = __shfl(dv, j);
      r2 += (od < dv || (od == dv && j < ln)) ? 1 : 0;
    }
    // redistribute rank->lane: lane r2 receives this lane's col
    myc = __builtin_amdgcn_ds_permute(r2 << 2, col);
  }
  if (ln < cK) {
    nbr[row * cK + ln] = myc;  // rank == lane
    atomicAdd(&cnt[bvert + myc], 1);
  }

  // fused v2e32: mean of h1 over this edge's 30 neighbors (quarter-wave)
  const unsigned* Xb = reinterpret_cast<const unsigned*>(h1 + bvert * cH);
  const int qg = ln >> 4, f2 = ln & 15;
  float s0 = 0.f, s1 = 0.f;
#pragma unroll
  for (int m = 0; m < 8; ++m) {
    int j = m * 4 + qg;
    int idx = __shfl(myc, j < cK ? j : 0);
    unsigned u = Xb[(size_t)idx * 16 + f2];
    bool ok = j < cK;
    s0 += ok ? bf16lo(u) : 0.f;
    s1 += ok ? bf16hi(u) : 0.f;
  }
  s0 += __shfl_xor(s0, 16);
  s1 += __shfl_xor(s1, 16);
  s0 += __shfl_xor(s0, 32);
  s1 += __shfl_xor(s1, 32);
  if (ln < 16) {
    BU cv;
    cv.b[0] = (__bf16)(s0 * (1.f / 30.f));
    cv.b[1] = (__bf16)(s1 * (1.f / 30.f));
    reinterpret_cast<unsigned*>(Y1)[row * 16 + f2] = cv.u;
  }
}

// ------- K3 (cooperative): scan | fill | e2v_t2 | v2e64 | e2v64 -----------
// 1024 blocks x 256 threads, grid.sync between phases. Bodies = verbatim
// ports of the R19 kernels; w2s staged once at entry.
__global__ __launch_bounds__(256, 4) void k_post(
    const int* __restrict__ cnt, int* __restrict__ rp,
    const int* __restrict__ nbr, int* __restrict__ cur, int* __restrict__ el,
    const __bf16* __restrict__ Y1, const float* __restrict__ w2,
    const float* __restrict__ b2, const float* __restrict__ g2,
    const float* __restrict__ be2, __bf16* __restrict__ h2,
    __bf16* __restrict__ Y2, float* __restrict__ out) {
  cg::grid_group grid = cg::this_grid();
  __shared__ float w2s[cH * cC];  // 8 KB
  __shared__ int wsum[4];
  const int t  = threadIdx.x;
  const int ln = t & 63;
  const int w  = t >> 6;
  for (int n = t; n < cH * cC; n += 256) w2s[n] = w2[n];

  // ---- phase 1: CSR scan (block b handles sample b; 13 elems/thread) ----
  if (blockIdx.x < cB) {
    const int b = blockIdx.x;
    const int* c = cnt + b * cL;
    int* r = rp + b * (cL + 1);
    int v[13];
    int s = 0;
    const int base = t * 13;  // 256*13 = 3328 >= 3136
#pragma unroll
    for (int i = 0; i < 13; ++i) {
      int idx = base + i;
      v[i] = (idx < cL) ? c[idx] : 0;
      s += v[i];
    }
    int inc = s;
#pragma unroll
    for (int off = 1; off < 64; off <<= 1) {
      int u = __shfl_up(inc, off);
      if (ln >= off) inc += u;
    }
    if (ln == 63) wsum[w] = inc;
    __syncthreads();
    int carry = 0;
#pragma unroll
    for (int i = 0; i < 4; ++i) carry += (i < w) ? wsum[i] : 0;
    int excl = carry + inc - s;  // exclusive prefix of this thread's segment
#pragma unroll
    for (int i = 0; i < 13; ++i) {
      int idx = base + i;
      if (idx < cL) r[idx] = excl;
      excl += v[i];
    }
    if (t == 255) r[cL] = excl;  // grand total (tail v[] all zero)
  }
  grid.sync();

  // ---- phase 2: CSR fill (grid-stride over 2940 x 256 work units) ----
  for (int u = blockIdx.x; u < (NV * cK) / 256; u += (int)gridDim.x) {
    int gidx = u * 256 + t;
    int b = gidx / (cL * cK);
    int e = (gidx / cK) % cL;
    int v = nbr[gidx];
    v = min(max(v, 0), cL - 1);  // clamp: garbage cannot become a wild write
    int p = rp[b * (cL + 1) + v] + atomicAdd(&cur[b * cL + v], 1);
    p = min(max(p, 0), cL * cK - 1);
    el[(size_t)b * cL * cK + p] = e;
  }
  grid.sync();

  // ---- phase 3: e2v(F=32) + relu + theta2 + bn (wave per vertex) ----
  for (int u = blockIdx.x; u < NV / 4; u += (int)gridDim.x) {
    const size_t vr = (size_t)u * 4 + w;  // b*cL + v
    const size_t b  = vr / cL;
    const int v = (int)(vr % cL);
    const int* rpb = rp + b * (cL + 1);
    const int s0 = rpb[v];
    const int deg = rpb[v + 1] - s0;  // >= 1 (self edge always selected)
    const int* elb = el + b * (size_t)cL * cK + s0;
    const __bf16* Yb = Y1 + b * cL * cH;
    const int hi = ln >> 5, f = ln & 31;
    float s = 0.f;
    for (int base2 = 0; base2 < deg; base2 += 64) {
      const int take = min(64, deg - base2);
      const int eidx = elb[base2 + (ln < take ? ln : 0)];  // parallel load
      for (int j0 = 0; j0 < take; j0 += 16) {  // 8 independent per half
        float acc = 0.f;
#pragma unroll
        for (int k2 = 0; k2 < 8; ++k2) {
          int j = j0 + 2 * k2 + hi;
          int e0 = __shfl(eidx, j < take ? j : 0);
          float y = (float)Yb[(size_t)e0 * cH + f];
          acc += (j < take) ? y : 0.f;
        }
        s += acc;
      }
    }
    s += __shfl_xor(s, 32);
    float r = fmaxf(s / (float)deg, 0.f);  // e2v mean + relu
    float s2 = 0.f;
#pragma unroll 8
    for (int k = 0; k < cH; ++k) {
      float rk = __shfl(r, k);
      s2 = fmaf(rk, w2s[k * cC + ln], s2);
    }
    h2[vr * cC + ln] = (__bf16)((s2 + b2[ln]) * (g2[ln] * BN_SC) + be2[ln]);
  }
  grid.sync();

  // ---- phase 4: v2e F=64 (wave per edge, uint-widened gathers) ----
  for (int u = blockIdx.x; u < NV / 4; u += (int)gridDim.x) {
    const size_t er = (size_t)u * 4 + w;  // b*cL + e
    const size_t b  = er / cL;
    const unsigned* Xb = reinterpret_cast<const unsigned*>(h2 + b * cL * cC);
    const int nb_l = nbr[er * cK + (ln < cK ? ln : cK - 1)];
    const int half = ln >> 5, f2 = ln & 31;
    int idx[15];
#pragma unroll
    for (int m = 0; m < 15; ++m) idx[m] = __shfl(nb_l, 2 * m + half);
    unsigned v[15];
#pragma unroll
    for (int m = 0; m < 15; ++m) v[m] = Xb[(size_t)idx[m] * 32 + f2];
    float s0 = 0.f, s1 = 0.f;
#pragma unroll
    for (int m = 0; m < 15; ++m) {
      s0 += bf16lo(v[m]);
      s1 += bf16hi(v[m]);
    }
    s0 += __shfl_xor(s0, 32);
    s1 += __shfl_xor(s1, 32);
    if (half == 0) {
      BU cv;
      cv.b[0] = (__bf16)(s0 * (1.f / 30.f));
      cv.b[1] = (__bf16)(s1 * (1.f / 30.f));
      reinterpret_cast<unsigned*>(Y2)[er * 32 + f2] = cv.u;
    }
  }
  grid.sync();

  // ---- phase 5: final e2v F=64, fp32 out ----
  for (int u = blockIdx.x; u < NV / 4; u += (int)gridDim.x) {
    const size_t vr = (size_t)u * 4 + w;  // b*cL + v
    const size_t b  = vr / cL;
    const int v = (int)(vr % cL);
    const int* rpb = rp + b * (cL + 1);
    const int s0r = rpb[v];
    const int deg = rpb[v + 1] - s0r;
    const int* elb = el + b * (size_t)cL * cK + s0r;
    const unsigned* Yb = reinterpret_cast<const unsigned*>(Y2 + b * cL * cC);
    const int half = ln >> 5, f2 = ln & 31;
    float s0 = 0.f, s1 = 0.f;
    for (int base2 = 0; base2 < deg; base2 += 64) {
      const int take = min(64, deg - base2);
      const int eidx = elb[base2 + (ln < take ? ln : 0)];
      for (int j0 = 0; j0 < take; j0 += 16) {  // 8 independent per half
        float a0 = 0.f, a1 = 0.f;
#pragma unroll
        for (int k2 = 0; k2 < 8; ++k2) {
          int j = j0 + 2 * k2 + half;
          int e0 = __shfl(eidx, j < take ? j : 0);
          unsigned uu = Yb[(size_t)e0 * 32 + f2];
          bool ok = j < take;
          a0 += ok ? bf16lo(uu) : 0.f;
          a1 += ok ? bf16hi(uu) : 0.f;
        }
        s0 += a0;
        s1 += a1;
      }
    }
    s0 += __shfl_xor(s0, 32);
    s1 += __shfl_xor(s1, 32);
    // redistribute: feature ln lives on lane ln>>1, component ln&1
    float v0 = __shfl(s0, ln >> 1);
    float v1 = __shfl(s1, ln >> 1);
    out[vr * cC + ln] = ((ln & 1) ? v1 : v0) / (float)deg;
  }
}

}  // namespace

extern "C" void kernel_launch(void* const* d_in, const int* in_sizes, int n_in,
                              void* d_out, int out_size, void* d_ws,
                              size_t ws_size, hipStream_t stream) {
  (void)in_sizes; (void)n_in; (void)out_size; (void)ws_size;
  const float* x   = (const float*)d_in[0];
  const float* w1  = (const float*)d_in[1];
  const float* b1  = (const float*)d_in[2];
  const float* g1  = (const float*)d_in[3];
  const float* be1 = (const float*)d_in[4];
  const float* w2  = (const float*)d_in[5];
  const float* b2  = (const float*)d_in[6];
  const float* g2  = (const float*)d_in[7];
  const float* be2 = (const float*)d_in[8];
  float* out = (float*)d_out;

  // workspace: ~27.5 MB peak (<= proven ~31.5 MB)
  char* base = (char*)d_ws;
  size_t off = 0;
  auto carve = [&](size_t bytes) {
    char* p = base + off;
    off += (bytes + 255) & ~(size_t)255;
    return p;
  };
  float* sqf = (float*)carve((size_t)NV * 4);
  int*   nbr = (int*)carve((size_t)NV * cK * 4);
  int*   rp  = (int*)carve((size_t)cB * (cL + 1) * 4);
  int*   cnt = (int*)carve((size_t)NV * 4);
  int*   cur = (int*)carve((size_t)NV * 4);
  // region A: {xhi|xlo} (dead after k_sweep) then {el}
  char* RA = carve((size_t)NV * 64 * 2 * 2);  // 6,422,528
  ushort* xhi = (ushort*)RA;
  ushort* xlo = (ushort*)(RA + 3211264);
  int* el = (int*)RA;
  // region C: candq [0, 8028160) live until rescore ends; h1/Y1 placed
  // AFTER it (fused rescore reads candq while writing Y1); h2/Y2 follow.
  char* RC = carve(17661952);
  unsigned* candq = (unsigned*)RC;                 // 8,028,160 B
  __bf16* h1 = (__bf16*)(RC + 8028160);            // 1.6 MB
  __bf16* Y1 = (__bf16*)(RC + 9633792);            // 1.6 MB
  __bf16* h2 = (__bf16*)(RC + 11239424);           // 3.2 MB
  __bf16* Y2 = (__bf16*)(RC + 14450688);           // 3.2 MB

  k_splitth<<<NV / 8, 256, 0, stream>>>(x, w1, b1, g1, be1, xhi, xlo, sqf,
                                        cnt, cur, h1);
  k_sweep<<<dim3(98, 2, cB), 128, 0, stream>>>(xhi, xlo, sqf, candq);
  k_rescore<<<NV / 4, 256, 0, stream>>>(x, candq, h1, nbr, cnt, Y1);

  void* kargs[] = {(void*)&cnt, (void*)&rp,  (void*)&nbr, (void*)&cur,
                   (void*)&el,  (void*)&Y1,  (void*)&w2,  (void*)&b2,
                   (void*)&g2,  (void*)&be2, (void*)&h2,  (void*)&Y2,
                   (void*)&out};
  hipLaunchCooperativeKernel((const void*)k_post, dim3(1024), dim3(256),
                             kargs, 0, stream);
}

// Round 8
// 870.978 us; speedup vs baseline: 1.0129x; 1.0129x over previous
//
#include <hip/hip_runtime.h>
#include <hip/hip_cooperative_groups.h>
#include <math.h>

namespace cg = cooperative_groups;

// HGNNPBlock: per-sample kNN hypergraph (k=30) + 2x (theta -> bn -> v2v mean).
// B=8, L=56*56=3136, C=64, hid=32.
//
// R21 = R19 front (splitth/sweep/rescore, measured 373.5us total) + k_post
// mega-kernel REDONE SPILL-FREE. R20 evidence: k_post VGPR_Count=32 while
// phase bodies carried idx[15]+v[15] arrays -> scratch spills (WRITE_SIZE
// 51MB vs ~16MB real output; VALUBusy 5.4%; 622us). Fixes:
//   - plain __launch_bounds__(256) (no min-waves hint),
//   - phase 1 scan: sum-then-RELOAD two-pass, no v[13] array,
//   - phase 4 v2e64: array-free gather loop (compiler picks in-flight depth),
//   - all phases hold <=8 live scalars.
// R20's useful measurement: R19 back half = ~114us incl 4 boundaries; a
// spill-free k_post should land 80-120us -> total ~340-360.
// Fallback: if WRITE_SIZE still inflated -> coop-kernel regalloc pathology
// is structural; revert to R19 8-kernel form.

namespace {

constexpr int cB = 8;
constexpr int cL = 3136;
constexpr int cC = 64;
constexpr int cH = 32;
constexpr int cK = 30;
constexpr int NV = cB * cL;   // 25088
constexpr int QD = 10;        // per-lane queue depth
constexpr float BN_SC = 0.99999500003749964f;  // 1/sqrt(1+1e-5) in fp32

typedef __bf16 bf16x8 __attribute__((ext_vector_type(8)));
typedef float floatx4 __attribute__((ext_vector_type(4)));

union BU {
  __bf16 b[2];
  unsigned u;
};

__device__ inline unsigned umin2(unsigned a, unsigned b) { return a < b ? a : b; }
__device__ inline unsigned umax2(unsigned a, unsigned b) { return a > b ? a : b; }
__device__ inline unsigned umin3(unsigned a, unsigned b, unsigned c) {
  return umin2(umin2(a, b), c);  // compiler fuses to v_min3_u32
}
__device__ inline float bf16lo(unsigned u) { return __uint_as_float(u << 16); }
__device__ inline float bf16hi(unsigned u) {
  return __uint_as_float(u & 0xFFFF0000u);
}

// sort a bitonic 64-sequence (one value per lane) ascending, shfl-only
__device__ inline unsigned bclean64(unsigned v, int ln) {
#pragma unroll
  for (int off = 32; off; off >>= 1) {
    unsigned p = (unsigned)__shfl_xor((int)v, off);
    v = (ln & off) ? umax2(v, p) : umin2(v, p);
  }
  return v;
}

// ------- K0: split + |x|^2 + theta1 + bn, fused (per-vertex maps over x) ---
// grid 3136 x 256: block = 8 vertices x 32 features. x staged in LDS once.
__global__ __launch_bounds__(256) void k_splitth(
    const float* __restrict__ x, const float* __restrict__ w1,
    const float* __restrict__ b1, const float* __restrict__ g1,
    const float* __restrict__ be1, ushort* __restrict__ xhi,
    ushort* __restrict__ xlo, float* __restrict__ sqf,
    int* __restrict__ cnt, int* __restrict__ cur, __bf16* __restrict__ h1) {
  __shared__ float w1s[cC * cH];  // 8 KB
  __shared__ float xs[8 * 64];    // 2 KB
  const int t = threadIdx.x;
  const int v0 = blockIdx.x * 8;
  for (int n = t; n < cC * cH; n += 256) w1s[n] = w1[n];
  {
    float2 xv = reinterpret_cast<const float2*>(x + (size_t)v0 * 64)[t];
    xs[2 * t] = xv.x;
    xs[2 * t + 1] = xv.y;
    BU hh, ll;
    hh.b[0] = (__bf16)xv.x;
    hh.b[1] = (__bf16)xv.y;
    ll.b[0] = (__bf16)(xv.x - (float)hh.b[0]);
    ll.b[1] = (__bf16)(xv.y - (float)hh.b[1]);
    reinterpret_cast<unsigned*>(xhi)[(size_t)v0 * 32 + t] = hh.u;
    reinterpret_cast<unsigned*>(xlo)[(size_t)v0 * 32 + t] = ll.u;
    float ss = xv.x * xv.x + xv.y * xv.y;  // row r = t>>5 spans lanes r*32..+31
#pragma unroll
    for (int off = 1; off < 32; off <<= 1) ss += __shfl_xor(ss, off);
    if ((t & 31) == 0) sqf[v0 + (t >> 5)] = ss * 1024.f + 262144.f;  // q20
  }
  if (t < 8) {
    cnt[v0 + t] = 0;
    cur[v0 + t] = 0;
  }
  __syncthreads();
  const int r = t >> 5, f = t & 31;
  float s = 0.f;
#pragma unroll
  for (int k = 0; k < cC; ++k) s = fmaf(xs[r * 64 + k], w1s[k * cH + f], s);
  h1[(size_t)(v0 + r) * cH + f] =
      (__bf16)((s + b1[f]) * (g1[f] * BN_SC) + be1[f]);
}

// ------- K1: fused gram sweep + branchless top-10 -> per-half top-40 ------
// grid (98, 2, 8): 32-row strip x col-half x sample. block 128 (2 waves);
// wave w rows w*16..w*16+15; lane (tx,qd) rows qd*4+e, cols f*16+tx (f<2).
__global__ __launch_bounds__(128, 4) void k_sweep(
    const ushort* __restrict__ xhi, const ushort* __restrict__ xlo,
    const float* __restrict__ sqf, unsigned* __restrict__ candq) {
  const int ib = blockIdx.x, qt = blockIdx.y, b = blockIdx.z;
  const int r0 = ib * 32;
  const int jb0 = qt * 1568;
  const int ntile = 49;  // 32-col tiles; 2 * 49*32 = 3136 (exact halves)
  const size_t bbase = (size_t)b * cL;

  __shared__ ushort aHi[32 * 72], aLo[32 * 72];  // stride 72: conflict-free
  __shared__ ushort bHi[32 * 72], bLo[32 * 72];
  __shared__ float sqJs[32];

  const int t  = threadIdx.x;  // 0..127
  const int ln = t & 63;
  const int w  = t >> 6;       // wave -> 16-row group
  const int tx = ln & 15;
  const int qd = ln >> 4;

#pragma unroll
  for (int it = 0; it < 2; ++it) {  // stage A strip (32 rows x 8 uint4 chunks)
    int idx = t + 128 * it;
    int r = idx >> 3, blk = idx & 7;
    *reinterpret_cast<uint4*>(&aHi[r * 72 + blk * 8]) =
        *reinterpret_cast<const uint4*>(&xhi[(bbase + r0 + r) * 64 + blk * 8]);
    *reinterpret_cast<uint4*>(&aLo[r * 72 + blk * 8]) =
        *reinterpret_cast<const uint4*>(&xlo[(bbase + r0 + r) * 64 + blk * 8]);
  }
  __syncthreads();

  bf16x8 aH[2], aL[2];
#pragma unroll
  for (int kk = 0; kk < 2; ++kk) {
    aH[kk] = *reinterpret_cast<const bf16x8*>(
        &aHi[(w * 16 + tx) * 72 + kk * 32 + qd * 8]);
    aL[kk] = *reinterpret_cast<const bf16x8*>(
        &aLo[(w * 16 + tx) * 72 + kk * 32 + qd * 8]);
  }

  unsigned q[4][QD];  // per-row sorted top-QD (ascending), packed q20|col12
#pragma unroll
  for (int e = 0; e < 4; ++e)
#pragma unroll
    for (int k = 0; k < QD; ++k) q[e][k] = 0xFFFFFFFFu;

  // register prefetch of B tiles (async-STAGE split)
  const int pr  = (t + 0)   >> 3, pblk  = (t + 0)   & 7;   // it=0 slot
  const int pr1 = (t + 128) >> 3, pblk1 = (t + 128) & 7;   // it=1 slot
  uint4 pH0, pH1, pL0, pL1;
  float pS = 0.f;
  {
    const int jb = jb0;
    pH0 = *reinterpret_cast<const uint4*>(&xhi[(bbase + jb + pr) * 64 + pblk * 8]);
    pL0 = *reinterpret_cast<const uint4*>(&xlo[(bbase + jb + pr) * 64 + pblk * 8]);
    pH1 = *reinterpret_cast<const uint4*>(&xhi[(bbase + jb + pr1) * 64 + pblk1 * 8]);
    pL1 = *reinterpret_cast<const uint4*>(&xlo[(bbase + jb + pr1) * 64 + pblk1 * 8]);
    if (t < 32) pS = sqf[bbase + jb + t];
  }

  for (int st = 0; st < ntile; ++st) {
    __syncthreads();  // prev compute done -> LDS writable; drains prefetch vmcnt
    *reinterpret_cast<uint4*>(&bHi[pr * 72 + pblk * 8])   = pH0;
    *reinterpret_cast<uint4*>(&bLo[pr * 72 + pblk * 8])   = pL0;
    *reinterpret_cast<uint4*>(&bHi[pr1 * 72 + pblk1 * 8]) = pH1;
    *reinterpret_cast<uint4*>(&bLo[pr1 * 72 + pblk1 * 8]) = pL1;
    if (t < 32) sqJs[t] = pS;
    __syncthreads();  // tile st ready

    // issue loads for tile st+1 NOW (after the barrier so its vmcnt(0) drain
    // doesn't eat them); they retire during the compute below.
    if (st + 1 < ntile) {
      const int jb = jb0 + (st + 1) * 32;
      pH0 = *reinterpret_cast<const uint4*>(&xhi[(bbase + jb + pr) * 64 + pblk * 8]);
      pL0 = *reinterpret_cast<const uint4*>(&xlo[(bbase + jb + pr) * 64 + pblk * 8]);
      pH1 = *reinterpret_cast<const uint4*>(&xhi[(bbase + jb + pr1) * 64 + pblk1 * 8]);
      pL1 = *reinterpret_cast<const uint4*>(&xlo[(bbase + jb + pr1) * 64 + pblk1 * 8]);
      if (t < 32) pS = sqf[bbase + jb + t];
    }
    __builtin_amdgcn_sched_barrier(0);  // keep prefetch issue above compute

    unsigned pk[2][4];  // packed candidates per f per e
#pragma unroll
    for (int f = 0; f < 2; ++f) {
      const int bro = (f * 16 + tx) * 72 + qd * 8;
      bf16x8 bh0 = *reinterpret_cast<const bf16x8*>(&bHi[bro]);
      bf16x8 bh1 = *reinterpret_cast<const bf16x8*>(&bHi[bro + 32]);
      bf16x8 bl0 = *reinterpret_cast<const bf16x8*>(&bLo[bro]);
      bf16x8 bl1 = *reinterpret_cast<const bf16x8*>(&bLo[bro + 32]);
      floatx4 acc = {0.f, 0.f, 0.f, 0.f};
      acc = __builtin_amdgcn_mfma_f32_16x16x32_bf16(aH[0], bh0, acc, 0, 0, 0);
      acc = __builtin_amdgcn_mfma_f32_16x16x32_bf16(aH[1], bh1, acc, 0, 0, 0);
      acc = __builtin_amdgcn_mfma_f32_16x16x32_bf16(aH[0], bl0, acc, 0, 0, 0);
      acc = __builtin_amdgcn_mfma_f32_16x16x32_bf16(aH[1], bl1, acc, 0, 0, 0);
      acc = __builtin_amdgcn_mfma_f32_16x16x32_bf16(aL[0], bh0, acc, 0, 0, 0);
      acc = __builtin_amdgcn_mfma_f32_16x16x32_bf16(aL[1], bh1, acc, 0, 0, 0);
      const float sjs = sqJs[f * 16 + tx];
      const unsigned col = (unsigned)(jb0 + st * 32 + f * 16 + tx);
#pragma unroll
      for (int e = 0; e < 4; ++e) {
        // q20 quantized d2 (|xi|^2 dropped: row-constant, ranks unaffected)
        float qf = fmaf(acc[e], -2048.f, sjs);
        qf = fminf(fmaxf(qf, 0.f), 1048575.f);  // clamp to 20 bits
        pk[f][e] = ((unsigned)qf << 12) | col;
      }
    }

    // branchless pair-insert: keep smallest QD of q U {a0,a1}, a0<=a1.
    // new_q[i] = min3(q[i], max(q[i-1],a0), max(q[i-2],a1)), descending i.
#pragma unroll
    for (int e = 0; e < 4; ++e) {
      unsigned a0 = umin2(pk[0][e], pk[1][e]);
      unsigned a1 = umax2(pk[0][e], pk[1][e]);
#pragma unroll
      for (int i = QD - 1; i >= 2; --i)
        q[e][i] = umin3(q[e][i], umax2(q[e][i - 1], a0),
                        umax2(q[e][i - 2], a1));
      q[e][1] = umin3(q[e][1], umax2(q[e][0], a0), a1);
      q[e][0] = umin3(q[e][0], a0, a1);
    }
  }

  // extraction: 40 wave-min pops per row; e-interleaved -> 4 independent
  // dependency chains in flight.
  unsigned* cr[4];
#pragma unroll
  for (int e = 0; e < 4; ++e)
    cr[e] = candq + (bbase + r0 + w * 16 + qd * 4 + e) * 80 + qt * 40;
  for (int it = 0; it < 40; ++it) {
    unsigned h0 = q[0][0], h1 = q[1][0], h2 = q[2][0], h3 = q[3][0];
    unsigned m0 = h0, m1 = h1, m2 = h2, m3 = h3;
#pragma unroll
    for (int off = 1; off < 16; off <<= 1) {
      m0 = umin2(m0, (unsigned)__shfl_xor((int)m0, off));
      m1 = umin2(m1, (unsigned)__shfl_xor((int)m1, off));
      m2 = umin2(m2, (unsigned)__shfl_xor((int)m2, off));
      m3 = umin2(m3, (unsigned)__shfl_xor((int)m3, off));
    }
    if (tx == 0) {
      cr[0][it] = m0;
      cr[1][it] = m1;
      cr[2][it] = m2;
      cr[3][it] = m3;
    }
    if (h0 == m0) {  // keys distinct (col in low bits) -> exactly one pop
#pragma unroll
      for (int k = 0; k < QD - 1; ++k) q[0][k] = q[0][k + 1];
      q[0][QD - 1] = 0xFFFFFFFFu;
    }
    if (h1 == m1) {
#pragma unroll
      for (int k = 0; k < QD - 1; ++k) q[1][k] = q[1][k + 1];
      q[1][QD - 1] = 0xFFFFFFFFu;
    }
    if (h2 == m2) {
#pragma unroll
      for (int k = 0; k < QD - 1; ++k) q[2][k] = q[2][k + 1];
      q[2][QD - 1] = 0xFFFFFFFFu;
    }
    if (h3 == m3) {
#pragma unroll
      for (int k = 0; k < QD - 1; ++k) q[3][k] = q[3][k + 1];
      q[3][QD - 1] = 0xFFFFFFFFu;
    }
  }
}

// ------- K2: merge 2 sorted lists + cond. fp64 re-rank + fused v2e32 ------
__global__ __launch_bounds__(256) void k_rescore(
    const float* __restrict__ x, const unsigned* __restrict__ candq,
    const __bf16* __restrict__ h1, int* __restrict__ nbr,
    int* __restrict__ cnt, __bf16* __restrict__ Y1) {
  const int w  = threadIdx.x >> 6;
  const int ln = threadIdx.x & 63;
  const size_t row = (size_t)blockIdx.x * 4 + w;
  const size_t bvert = row - (row % cL);  // b*cL

  const unsigned* cq = candq + row * 80;
  unsigned A = (ln < 40) ? cq[ln]      : 0xFFFFFFFFu;
  unsigned B = (ln < 40) ? cq[40 + ln] : 0xFFFFFFFFu;

  // split-min + bitonic clean: sorted lower-64 of the 2-list union
  unsigned g = umin2(A, (unsigned)__shfl((int)B, 63 - ln));
  g = bclean64(g, ln);  // sorted asc; lanes 0..39 = global top-40 (all real)

  const unsigned qv = g >> 12;  // 20-bit quantized distance
  const int col = min((int)(g & 0xFFFu), cL - 1);  // clamp: garbage-proof

  // quantized gap at the 29/30 boundary (sorted -> just neighbors)
  unsigned q29 = (unsigned)__shfl((int)qv, 29);
  unsigned q30 = (unsigned)__shfl((int)qv, 30);
  int myc = col;  // fast path: lane == rank already
  if (!(q30 > q29 + 6)) {  // wave-uniform branch
    // ambiguous boundary: exact fp64 re-rank of the 40 merged candidates
    float4 xi[16];
    const float4* xi4 = reinterpret_cast<const float4*>(x + row * 64);
#pragma unroll
    for (int c = 0; c < 16; ++c) xi[c] = xi4[c];
    double dv = 1e300;
    if (ln < 40) {
      const float4* xj4 =
          reinterpret_cast<const float4*>(x + (bvert + col) * 64);
      double ax = 0.0, ay = 0.0, az = 0.0, aw = 0.0;
#pragma unroll
      for (int c = 0; c < 16; ++c) {
        float4 xj = xj4[c];
        double d0 = (double)xi[c].x - (double)xj.x; ax = fma(d0, d0, ax);
        double d1 = (double)xi[c].y - (double)xj.y; ay = fma(d1, d1, ay);
        double d2 = (double)xi[c].z - (double)xj.z; az = fma(d2, d2, az);
        double d3 = (double)xi[c].w - (double)xj.w; aw = fma(d3, d3, aw);
      }
      dv = (ax + ay) + (az + aw);
    }
    int r2 = 0;
    for (int j = 0; j < 40; ++j) {
      double od = __shfl(dv, j);
      r2 += (od < dv || (od == dv && j < ln)) ? 1 : 0;
    }
    // redistribute rank->lane: lane r2 receives this lane's col
    myc = __builtin_amdgcn_ds_permute(r2 << 2, col);
  }
  if (ln < cK) {
    nbr[row * cK + ln] = myc;  // rank == lane
    atomicAdd(&cnt[bvert + myc], 1);
  }

  // fused v2e32: mean of h1 over this edge's 30 neighbors (quarter-wave)
  const unsigned* Xb = reinterpret_cast<const unsigned*>(h1 + bvert * cH);
  const int qg = ln >> 4, f2 = ln & 15;
  float s0 = 0.f, s1 = 0.f;
#pragma unroll
  for (int m = 0; m < 8; ++m) {
    int j = m * 4 + qg;
    int idx = __shfl(myc, j < cK ? j : 0);
    unsigned u = Xb[(size_t)idx * 16 + f2];
    bool ok = j < cK;
    s0 += ok ? bf16lo(u) : 0.f;
    s1 += ok ? bf16hi(u) : 0.f;
  }
  s0 += __shfl_xor(s0, 16);
  s1 += __shfl_xor(s1, 16);
  s0 += __shfl_xor(s0, 32);
  s1 += __shfl_xor(s1, 32);
  if (ln < 16) {
    BU cv;
    cv.b[0] = (__bf16)(s0 * (1.f / 30.f));
    cv.b[1] = (__bf16)(s1 * (1.f / 30.f));
    reinterpret_cast<unsigned*>(Y1)[row * 16 + f2] = cv.u;
  }
}

// ------- K3 (cooperative): scan | fill | e2v_t2 | v2e64 | e2v64 -----------
// 1024 blocks x 256 threads, grid.sync between phases. SPILL-FREE: every
// phase holds <=8 live scalars; no register arrays; scan reloads instead of
// caching 13 elems; plain launch_bounds (no min-waves squeeze trigger).
__global__ __launch_bounds__(256) void k_post(
    const int* __restrict__ cnt, int* __restrict__ rp,
    const int* __restrict__ nbr, int* __restrict__ cur, int* __restrict__ el,
    const __bf16* __restrict__ Y1, const float* __restrict__ w2,
    const float* __restrict__ b2, const float* __restrict__ g2,
    const float* __restrict__ be2, __bf16* __restrict__ h2,
    __bf16* __restrict__ Y2, float* __restrict__ out) {
  cg::grid_group grid = cg::this_grid();
  __shared__ float w2s[cH * cC];  // 8 KB
  __shared__ int wsum[4];
  const int t  = threadIdx.x;
  const int ln = t & 63;
  const int w  = t >> 6;
  for (int n = t; n < cH * cC; n += 256) w2s[n] = w2[n];

  // ---- phase 1: CSR scan (block b = sample b; sum-then-reload, no array) --
  if (blockIdx.x < cB) {
    const int b = blockIdx.x;
    const int* c = cnt + b * cL;
    int* r = rp + b * (cL + 1);
    const int base = t * 13;  // 256*13 = 3328 >= 3136
    int s = 0;
#pragma unroll 13
    for (int i = 0; i < 13; ++i) {
      int idx = base + i;
      s += (idx < cL) ? c[idx] : 0;
    }
    int inc = s;
#pragma unroll
    for (int off = 1; off < 64; off <<= 1) {
      int u = __shfl_up(inc, off);
      if (ln >= off) inc += u;
    }
    if (ln == 63) wsum[w] = inc;
    __syncthreads();
    int carry = 0;
#pragma unroll
    for (int i = 0; i < 4; ++i) carry += (i < w) ? wsum[i] : 0;
    int excl = carry + inc - s;  // exclusive prefix of this thread's segment
    for (int i = 0; i < 13; ++i) {  // reload (L1-hot) instead of array
      int idx = base + i;
      int vv = (idx < cL) ? c[idx] : 0;
      if (idx < cL) r[idx] = excl;
      excl += vv;
    }
    if (t == 255) r[cL] = excl;  // grand total
  }
  grid.sync();

  // ---- phase 2: CSR fill (grid-stride; scalar-only) ----
  for (int u = blockIdx.x; u < (NV * cK) / 256; u += (int)gridDim.x) {
    int gidx = u * 256 + t;
    int b = gidx / (cL * cK);
    int e = (gidx / cK) % cL;
    int v = nbr[gidx];
    v = min(max(v, 0), cL - 1);  // clamp: garbage cannot become a wild write
    int p = rp[b * (cL + 1) + v] + atomicAdd(&cur[b * cL + v], 1);
    p = min(max(p, 0), cL * cK - 1);
    el[(size_t)b * cL * cK + p] = e;
  }
  grid.sync();

  // ---- phase 3: e2v(F=32) + relu + theta2 + bn (wave per vertex) ----
  for (int u = blockIdx.x; u < NV / 4; u += (int)gridDim.x) {
    const size_t vr = (size_t)u * 4 + w;  // b*cL + v
    const size_t b  = vr / cL;
    const int v = (int)(vr % cL);
    const int* rpb = rp + b * (cL + 1);
    const int s0 = rpb[v];
    const int deg = rpb[v + 1] - s0;  // >= 1 (self edge always selected)
    const int* elb = el + b * (size_t)cL * cK + s0;
    const __bf16* Yb = Y1 + b * cL * cH;
    const int hi = ln >> 5, f = ln & 31;
    float s = 0.f;
    for (int base2 = 0; base2 < deg; base2 += 64) {
      const int take = min(64, deg - base2);
      const int eidx = elb[base2 + (ln < take ? ln : 0)];  // parallel load
      for (int j0 = 0; j0 < take; j0 += 16) {  // 8 independent per half
        float acc = 0.f;
#pragma unroll
        for (int k2 = 0; k2 < 8; ++k2) {
          int j = j0 + 2 * k2 + hi;
          int e0 = __shfl(eidx, j < take ? j : 0);
          float y = (float)Yb[(size_t)e0 * cH + f];
          acc += (j < take) ? y : 0.f;
        }
        s += acc;
      }
    }
    s += __shfl_xor(s, 32);
    float r = fmaxf(s / (float)deg, 0.f);  // e2v mean + relu
    float s2 = 0.f;
#pragma unroll 8
    for (int k = 0; k < cH; ++k) {
      float rk = __shfl(r, k);
      s2 = fmaf(rk, w2s[k * cC + ln], s2);
    }
    h2[vr * cC + ln] = (__bf16)((s2 + b2[ln]) * (g2[ln] * BN_SC) + be2[ln]);
  }
  grid.sync();

  // ---- phase 4: v2e F=64 (wave per edge; array-free gather loop) ----
  for (int u = blockIdx.x; u < NV / 4; u += (int)gridDim.x) {
    const size_t er = (size_t)u * 4 + w;  // b*cL + e
    const size_t b  = er / cL;
    const unsigned* Xb = reinterpret_cast<const unsigned*>(h2 + b * cL * cC);
    const int nb_l = nbr[er * cK + (ln < cK ? ln : cK - 1)];
    const int half = ln >> 5, f2 = ln & 31;
    float s0 = 0.f, s1 = 0.f;
#pragma unroll 5
    for (int m = 0; m < 15; ++m) {
      int e0 = __shfl(nb_l, 2 * m + half);
      unsigned uu = Xb[(size_t)e0 * 32 + f2];
      s0 += bf16lo(uu);
      s1 += bf16hi(uu);
    }
    s0 += __shfl_xor(s0, 32);
    s1 += __shfl_xor(s1, 32);
    if (half == 0) {
      BU cv;
      cv.b[0] = (__bf16)(s0 * (1.f / 30.f));
      cv.b[1] = (__bf16)(s1 * (1.f / 30.f));
      reinterpret_cast<unsigned*>(Y2)[er * 32 + f2] = cv.u;
    }
  }
  grid.sync();

  // ---- phase 5: final e2v F=64, fp32 out (scalar-only) ----
  for (int u = blockIdx.x; u < NV / 4; u += (int)gridDim.x) {
    const size_t vr = (size_t)u * 4 + w;  // b*cL + v
    const size_t b  = vr / cL;
    const int v = (int)(vr % cL);
    const int* rpb = rp + b * (cL + 1);
    const int s0r = rpb[v];
    const int deg = rpb[v + 1] - s0r;
    const int* elb = el + b * (size_t)cL * cK + s0r;
    const unsigned* Yb = reinterpret_cast<const unsigned*>(Y2 + b * cL * cC);
    const int half = ln >> 5, f2 = ln & 31;
    float s0 = 0.f, s1 = 0.f;
    for (int base2 = 0; base2 < deg; base2 += 64) {
      const int take = min(64, deg - base2);
      const int eidx = elb[base2 + (ln < take ? ln : 0)];
      for (int j0 = 0; j0 < take; j0 += 16) {  // 8 independent per half
        float a0 = 0.f, a1 = 0.f;
#pragma unroll
        for (int k2 = 0; k2 < 8; ++k2) {
          int j = j0 + 2 * k2 + half;
          int e0 = __shfl(eidx, j < take ? j : 0);
          unsigned uu = Yb[(size_t)e0 * 32 + f2];
          bool ok = j < take;
          a0 += ok ? bf16lo(uu) : 0.f;
          a1 += ok ? bf16hi(uu) : 0.f;
        }
        s0 += a0;
        s1 += a1;
      }
    }
    s0 += __shfl_xor(s0, 32);
    s1 += __shfl_xor(s1, 32);
    // redistribute: feature ln lives on lane ln>>1, component ln&1
    float v0 = __shfl(s0, ln >> 1);
    float v1 = __shfl(s1, ln >> 1);
    out[vr * cC + ln] = ((ln & 1) ? v1 : v0) / (float)deg;
  }
}

}  // namespace

extern "C" void kernel_launch(void* const* d_in, const int* in_sizes, int n_in,
                              void* d_out, int out_size, void* d_ws,
                              size_t ws_size, hipStream_t stream) {
  (void)in_sizes; (void)n_in; (void)out_size; (void)ws_size;
  const float* x   = (const float*)d_in[0];
  const float* w1  = (const float*)d_in[1];
  const float* b1  = (const float*)d_in[2];
  const float* g1  = (const float*)d_in[3];
  const float* be1 = (const float*)d_in[4];
  const float* w2  = (const float*)d_in[5];
  const float* b2  = (const float*)d_in[6];
  const float* g2  = (const float*)d_in[7];
  const float* be2 = (const float*)d_in[8];
  float* out = (float*)d_out;

  // workspace: ~27.5 MB peak (<= proven ~31.5 MB)
  char* base = (char*)d_ws;
  size_t off = 0;
  auto carve = [&](size_t bytes) {
    char* p = base + off;
    off += (bytes + 255) & ~(size_t)255;
    return p;
  };
  float* sqf = (float*)carve((size_t)NV * 4);
  int*   nbr = (int*)carve((size_t)NV * cK * 4);
  int*   rp  = (int*)carve((size_t)cB * (cL + 1) * 4);
  int*   cnt = (int*)carve((size_t)NV * 4);
  int*   cur = (int*)carve((size_t)NV * 4);
  // region A: {xhi|xlo} (dead after k_sweep) then {el}
  char* RA = carve((size_t)NV * 64 * 2 * 2);  // 6,422,528
  ushort* xhi = (ushort*)RA;
  ushort* xlo = (ushort*)(RA + 3211264);
  int* el = (int*)RA;
  // region C: candq [0, 8028160) live until rescore ends; h1/Y1 placed
  // AFTER it (fused rescore reads candq while writing Y1); h2/Y2 follow.
  char* RC = carve(17661952);
  unsigned* candq = (unsigned*)RC;                 // 8,028,160 B
  __bf16* h1 = (__bf16*)(RC + 8028160);            // 1.6 MB
  __bf16* Y1 = (__bf16*)(RC + 9633792);            // 1.6 MB
  __bf16* h2 = (__bf16*)(RC + 11239424);           // 3.2 MB
  __bf16* Y2 = (__bf16*)(RC + 14450688);           // 3.2 MB

  k_splitth<<<NV / 8, 256, 0, stream>>>(x, w1, b1, g1, be1, xhi, xlo, sqf,
                                        cnt, cur, h1);
  k_sweep<<<dim3(98, 2, cB), 128, 0, stream>>>(xhi, xlo, sqf, candq);
  k_rescore<<<NV / 4, 256, 0, stream>>>(x, candq, h1, nbr, cnt, Y1);

  void* kargs[] = {(void*)&cnt, (void*)&rp,  (void*)&nbr, (void*)&cur,
                   (void*)&el,  (void*)&Y1,  (void*)&w2,  (void*)&b2,
                   (void*)&g2,  (void*)&be2, (void*)&h2,  (void*)&Y2,
                   (void*)&out};
  hipLaunchCooperativeKernel((const void*)k_post, dim3(1024), dim3(256),
                             kargs, 0, stream);
}

// Round 9
// 447.102 us; speedup vs baseline: 1.9732x; 1.9481x over previous
//
#include <hip/hip_runtime.h>
#include <math.h>

// HGNNPBlock: per-sample kNN hypergraph (k=30) + 2x (theta -> bn -> v2v mean).
// B=8, L=56*56=3136, C=64, hid=32.
//
// R22 = R19 (373.5us, best) + ONE legal merge: k_scan+k_fill -> k_scanfill.
//   R20/R21 verdict: cooperative grid.sync on gfx950 = L2 writeback/inv per
//   sync (multi-XCD coherence) -> back-half intermediates (L2-resident in
//   the 8-kernel form) get flushed to HBM; WRITE_SIZE 51MB vs 16MB real,
//   145 GB/s, 620us. Mega-kernel structurally wrong on CDNA4. Reverted.
//   Boundary cost recalibrated from R18 fusion data: ~8.5us/launch.
//   k_scanfill: fill's dep on scan is SAMPLE-LOCAL -> one 1024-thr block
//   per sample does scan -> __syncthreads -> fill. cur[] moves to LDS
//   (ds atomics, 12.5KB/block) -- global cur array + zeroing eliminated.
// Everything else identical to R19.

namespace {

constexpr int cB = 8;
constexpr int cL = 3136;
constexpr int cC = 64;
constexpr int cH = 32;
constexpr int cK = 30;
constexpr int NV = cB * cL;   // 25088
constexpr int QD = 10;        // per-lane queue depth
constexpr float BN_SC = 0.99999500003749964f;  // 1/sqrt(1+1e-5) in fp32

typedef __bf16 bf16x8 __attribute__((ext_vector_type(8)));
typedef float floatx4 __attribute__((ext_vector_type(4)));

union BU {
  __bf16 b[2];
  unsigned u;
};

__device__ inline unsigned umin2(unsigned a, unsigned b) { return a < b ? a : b; }
__device__ inline unsigned umax2(unsigned a, unsigned b) { return a > b ? a : b; }
__device__ inline unsigned umin3(unsigned a, unsigned b, unsigned c) {
  return umin2(umin2(a, b), c);  // compiler fuses to v_min3_u32
}
__device__ inline float bf16lo(unsigned u) { return __uint_as_float(u << 16); }
__device__ inline float bf16hi(unsigned u) {
  return __uint_as_float(u & 0xFFFF0000u);
}

// sort a bitonic 64-sequence (one value per lane) ascending, shfl-only
__device__ inline unsigned bclean64(unsigned v, int ln) {
#pragma unroll
  for (int off = 32; off; off >>= 1) {
    unsigned p = (unsigned)__shfl_xor((int)v, off);
    v = (ln & off) ? umax2(v, p) : umin2(v, p);
  }
  return v;
}

// ------- K0: split + |x|^2 + theta1 + bn, fused (per-vertex maps over x) ---
// grid 3136 x 256: block = 8 vertices x 32 features. x staged in LDS once.
__global__ __launch_bounds__(256) void k_splitth(
    const float* __restrict__ x, const float* __restrict__ w1,
    const float* __restrict__ b1, const float* __restrict__ g1,
    const float* __restrict__ be1, ushort* __restrict__ xhi,
    ushort* __restrict__ xlo, float* __restrict__ sqf,
    int* __restrict__ cnt, __bf16* __restrict__ h1) {
  __shared__ float w1s[cC * cH];  // 8 KB
  __shared__ float xs[8 * 64];    // 2 KB
  const int t = threadIdx.x;
  const int v0 = blockIdx.x * 8;
  for (int n = t; n < cC * cH; n += 256) w1s[n] = w1[n];
  {
    float2 xv = reinterpret_cast<const float2*>(x + (size_t)v0 * 64)[t];
    xs[2 * t] = xv.x;
    xs[2 * t + 1] = xv.y;
    BU hh, ll;
    hh.b[0] = (__bf16)xv.x;
    hh.b[1] = (__bf16)xv.y;
    ll.b[0] = (__bf16)(xv.x - (float)hh.b[0]);
    ll.b[1] = (__bf16)(xv.y - (float)hh.b[1]);
    reinterpret_cast<unsigned*>(xhi)[(size_t)v0 * 32 + t] = hh.u;
    reinterpret_cast<unsigned*>(xlo)[(size_t)v0 * 32 + t] = ll.u;
    float ss = xv.x * xv.x + xv.y * xv.y;  // row r = t>>5 spans lanes r*32..+31
#pragma unroll
    for (int off = 1; off < 32; off <<= 1) ss += __shfl_xor(ss, off);
    if ((t & 31) == 0) sqf[v0 + (t >> 5)] = ss * 1024.f + 262144.f;  // q20
  }
  if (t < 8) cnt[v0 + t] = 0;
  __syncthreads();
  const int r = t >> 5, f = t & 31;
  float s = 0.f;
#pragma unroll
  for (int k = 0; k < cC; ++k) s = fmaf(xs[r * 64 + k], w1s[k * cH + f], s);
  h1[(size_t)(v0 + r) * cH + f] =
      (__bf16)((s + b1[f]) * (g1[f] * BN_SC) + be1[f]);
}

// ------- K1: fused gram sweep + branchless top-10 -> per-half top-40 ------
// grid (98, 2, 8): 32-row strip x col-half x sample. block 128 (2 waves);
// wave w rows w*16..w*16+15; lane (tx,qd) rows qd*4+e, cols f*16+tx (f<2).
__global__ __launch_bounds__(128, 4) void k_sweep(
    const ushort* __restrict__ xhi, const ushort* __restrict__ xlo,
    const float* __restrict__ sqf, unsigned* __restrict__ candq) {
  const int ib = blockIdx.x, qt = blockIdx.y, b = blockIdx.z;
  const int r0 = ib * 32;
  const int jb0 = qt * 1568;
  const int ntile = 49;  // 32-col tiles; 2 * 49*32 = 3136 (exact halves)
  const size_t bbase = (size_t)b * cL;

  __shared__ ushort aHi[32 * 72], aLo[32 * 72];  // stride 72: conflict-free
  __shared__ ushort bHi[32 * 72], bLo[32 * 72];
  __shared__ float sqJs[32];

  const int t  = threadIdx.x;  // 0..127
  const int ln = t & 63;
  const int w  = t >> 6;       // wave -> 16-row group
  const int tx = ln & 15;
  const int qd = ln >> 4;

#pragma unroll
  for (int it = 0; it < 2; ++it) {  // stage A strip (32 rows x 8 uint4 chunks)
    int idx = t + 128 * it;
    int r = idx >> 3, blk = idx & 7;
    *reinterpret_cast<uint4*>(&aHi[r * 72 + blk * 8]) =
        *reinterpret_cast<const uint4*>(&xhi[(bbase + r0 + r) * 64 + blk * 8]);
    *reinterpret_cast<uint4*>(&aLo[r * 72 + blk * 8]) =
        *reinterpret_cast<const uint4*>(&xlo[(bbase + r0 + r) * 64 + blk * 8]);
  }
  __syncthreads();

  bf16x8 aH[2], aL[2];
#pragma unroll
  for (int kk = 0; kk < 2; ++kk) {
    aH[kk] = *reinterpret_cast<const bf16x8*>(
        &aHi[(w * 16 + tx) * 72 + kk * 32 + qd * 8]);
    aL[kk] = *reinterpret_cast<const bf16x8*>(
        &aLo[(w * 16 + tx) * 72 + kk * 32 + qd * 8]);
  }

  unsigned q[4][QD];  // per-row sorted top-QD (ascending), packed q20|col12
#pragma unroll
  for (int e = 0; e < 4; ++e)
#pragma unroll
    for (int k = 0; k < QD; ++k) q[e][k] = 0xFFFFFFFFu;

  // register prefetch of B tiles (async-STAGE split)
  const int pr  = (t + 0)   >> 3, pblk  = (t + 0)   & 7;   // it=0 slot
  const int pr1 = (t + 128) >> 3, pblk1 = (t + 128) & 7;   // it=1 slot
  uint4 pH0, pH1, pL0, pL1;
  float pS = 0.f;
  {
    const int jb = jb0;
    pH0 = *reinterpret_cast<const uint4*>(&xhi[(bbase + jb + pr) * 64 + pblk * 8]);
    pL0 = *reinterpret_cast<const uint4*>(&xlo[(bbase + jb + pr) * 64 + pblk * 8]);
    pH1 = *reinterpret_cast<const uint4*>(&xhi[(bbase + jb + pr1) * 64 + pblk1 * 8]);
    pL1 = *reinterpret_cast<const uint4*>(&xlo[(bbase + jb + pr1) * 64 + pblk1 * 8]);
    if (t < 32) pS = sqf[bbase + jb + t];
  }

  for (int st = 0; st < ntile; ++st) {
    __syncthreads();  // prev compute done -> LDS writable; drains prefetch vmcnt
    *reinterpret_cast<uint4*>(&bHi[pr * 72 + pblk * 8])   = pH0;
    *reinterpret_cast<uint4*>(&bLo[pr * 72 + pblk * 8])   = pL0;
    *reinterpret_cast<uint4*>(&bHi[pr1 * 72 + pblk1 * 8]) = pH1;
    *reinterpret_cast<uint4*>(&bLo[pr1 * 72 + pblk1 * 8]) = pL1;
    if (t < 32) sqJs[t] = pS;
    __syncthreads();  // tile st ready

    // issue loads for tile st+1 NOW (after the barrier so its vmcnt(0) drain
    // doesn't eat them); they retire during the compute below.
    if (st + 1 < ntile) {
      const int jb = jb0 + (st + 1) * 32;
      pH0 = *reinterpret_cast<const uint4*>(&xhi[(bbase + jb + pr) * 64 + pblk * 8]);
      pL0 = *reinterpret_cast<const uint4*>(&xlo[(bbase + jb + pr) * 64 + pblk * 8]);
      pH1 = *reinterpret_cast<const uint4*>(&xhi[(bbase + jb + pr1) * 64 + pblk1 * 8]);
      pL1 = *reinterpret_cast<const uint4*>(&xlo[(bbase + jb + pr1) * 64 + pblk1 * 8]);
      if (t < 32) pS = sqf[bbase + jb + t];
    }
    __builtin_amdgcn_sched_barrier(0);  // keep prefetch issue above compute

    unsigned pk[2][4];  // packed candidates per f per e
#pragma unroll
    for (int f = 0; f < 2; ++f) {
      const int bro = (f * 16 + tx) * 72 + qd * 8;
      bf16x8 bh0 = *reinterpret_cast<const bf16x8*>(&bHi[bro]);
      bf16x8 bh1 = *reinterpret_cast<const bf16x8*>(&bHi[bro + 32]);
      bf16x8 bl0 = *reinterpret_cast<const bf16x8*>(&bLo[bro]);
      bf16x8 bl1 = *reinterpret_cast<const bf16x8*>(&bLo[bro + 32]);
      floatx4 acc = {0.f, 0.f, 0.f, 0.f};
      acc = __builtin_amdgcn_mfma_f32_16x16x32_bf16(aH[0], bh0, acc, 0, 0, 0);
      acc = __builtin_amdgcn_mfma_f32_16x16x32_bf16(aH[1], bh1, acc, 0, 0, 0);
      acc = __builtin_amdgcn_mfma_f32_16x16x32_bf16(aH[0], bl0, acc, 0, 0, 0);
      acc = __builtin_amdgcn_mfma_f32_16x16x32_bf16(aH[1], bl1, acc, 0, 0, 0);
      acc = __builtin_amdgcn_mfma_f32_16x16x32_bf16(aL[0], bh0, acc, 0, 0, 0);
      acc = __builtin_amdgcn_mfma_f32_16x16x32_bf16(aL[1], bh1, acc, 0, 0, 0);
      const float sjs = sqJs[f * 16 + tx];
      const unsigned col = (unsigned)(jb0 + st * 32 + f * 16 + tx);
#pragma unroll
      for (int e = 0; e < 4; ++e) {
        // q20 quantized d2 (|xi|^2 dropped: row-constant, ranks unaffected)
        float qf = fmaf(acc[e], -2048.f, sjs);
        qf = fminf(fmaxf(qf, 0.f), 1048575.f);  // clamp to 20 bits
        pk[f][e] = ((unsigned)qf << 12) | col;
      }
    }

    // branchless pair-insert: keep smallest QD of q U {a0,a1}, a0<=a1.
    // new_q[i] = min3(q[i], max(q[i-1],a0), max(q[i-2],a1)), descending i.
#pragma unroll
    for (int e = 0; e < 4; ++e) {
      unsigned a0 = umin2(pk[0][e], pk[1][e]);
      unsigned a1 = umax2(pk[0][e], pk[1][e]);
#pragma unroll
      for (int i = QD - 1; i >= 2; --i)
        q[e][i] = umin3(q[e][i], umax2(q[e][i - 1], a0),
                        umax2(q[e][i - 2], a1));
      q[e][1] = umin3(q[e][1], umax2(q[e][0], a0), a1);
      q[e][0] = umin3(q[e][0], a0, a1);
    }
  }

  // extraction: 40 wave-min pops per row; e-interleaved -> 4 independent
  // dependency chains in flight.
  unsigned* cr[4];
#pragma unroll
  for (int e = 0; e < 4; ++e)
    cr[e] = candq + (bbase + r0 + w * 16 + qd * 4 + e) * 80 + qt * 40;
  for (int it = 0; it < 40; ++it) {
    unsigned h0 = q[0][0], h1 = q[1][0], h2 = q[2][0], h3 = q[3][0];
    unsigned m0 = h0, m1 = h1, m2 = h2, m3 = h3;
#pragma unroll
    for (int off = 1; off < 16; off <<= 1) {
      m0 = umin2(m0, (unsigned)__shfl_xor((int)m0, off));
      m1 = umin2(m1, (unsigned)__shfl_xor((int)m1, off));
      m2 = umin2(m2, (unsigned)__shfl_xor((int)m2, off));
      m3 = umin2(m3, (unsigned)__shfl_xor((int)m3, off));
    }
    if (tx == 0) {
      cr[0][it] = m0;
      cr[1][it] = m1;
      cr[2][it] = m2;
      cr[3][it] = m3;
    }
    if (h0 == m0) {  // keys distinct (col in low bits) -> exactly one pop
#pragma unroll
      for (int k = 0; k < QD - 1; ++k) q[0][k] = q[0][k + 1];
      q[0][QD - 1] = 0xFFFFFFFFu;
    }
    if (h1 == m1) {
#pragma unroll
      for (int k = 0; k < QD - 1; ++k) q[1][k] = q[1][k + 1];
      q[1][QD - 1] = 0xFFFFFFFFu;
    }
    if (h2 == m2) {
#pragma unroll
      for (int k = 0; k < QD - 1; ++k) q[2][k] = q[2][k + 1];
      q[2][QD - 1] = 0xFFFFFFFFu;
    }
    if (h3 == m3) {
#pragma unroll
      for (int k = 0; k < QD - 1; ++k) q[3][k] = q[3][k + 1];
      q[3][QD - 1] = 0xFFFFFFFFu;
    }
  }
}

// ------- K2: merge 2 sorted lists + cond. fp64 re-rank + fused v2e32 ------
__global__ __launch_bounds__(256) void k_rescore(
    const float* __restrict__ x, const unsigned* __restrict__ candq,
    const __bf16* __restrict__ h1, int* __restrict__ nbr,
    int* __restrict__ cnt, __bf16* __restrict__ Y1) {
  const int w  = threadIdx.x >> 6;
  const int ln = threadIdx.x & 63;
  const size_t row = (size_t)blockIdx.x * 4 + w;
  const size_t bvert = row - (row % cL);  // b*cL

  const unsigned* cq = candq + row * 80;
  unsigned A = (ln < 40) ? cq[ln]      : 0xFFFFFFFFu;
  unsigned B = (ln < 40) ? cq[40 + ln] : 0xFFFFFFFFu;

  // split-min + bitonic clean: sorted lower-64 of the 2-list union
  unsigned g = umin2(A, (unsigned)__shfl((int)B, 63 - ln));
  g = bclean64(g, ln);  // sorted asc; lanes 0..39 = global top-40 (all real)

  const unsigned qv = g >> 12;  // 20-bit quantized distance
  const int col = min((int)(g & 0xFFFu), cL - 1);  // clamp: garbage-proof

  // quantized gap at the 29/30 boundary (sorted -> just neighbors)
  unsigned q29 = (unsigned)__shfl((int)qv, 29);
  unsigned q30 = (unsigned)__shfl((int)qv, 30);
  int myc = col;  // fast path: lane == rank already
  if (!(q30 > q29 + 6)) {  // wave-uniform branch
    // ambiguous boundary: exact fp64 re-rank of the 40 merged candidates
    float4 xi[16];
    const float4* xi4 = reinterpret_cast<const float4*>(x + row * 64);
#pragma unroll
    for (int c = 0; c < 16; ++c) xi[c] = xi4[c];
    double dv = 1e300;
    if (ln < 40) {
      const float4* xj4 =
          reinterpret_cast<const float4*>(x + (bvert + col) * 64);
      double ax = 0.0, ay = 0.0, az = 0.0, aw = 0.0;
#pragma unroll
      for (int c = 0; c < 16; ++c) {
        float4 xj = xj4[c];
        double d0 = (double)xi[c].x - (double)xj.x; ax = fma(d0, d0, ax);
        double d1 = (double)xi[c].y - (double)xj.y; ay = fma(d1, d1, ay);
        double d2 = (double)xi[c].z - (double)xj.z; az = fma(d2, d2, az);
        double d3 = (double)xi[c].w - (double)xj.w; aw = fma(d3, d3, aw);
      }
      dv = (ax + ay) + (az + aw);
    }
    int r2 = 0;
    for (int j = 0; j < 40; ++j) {
      double od = __shfl(dv, j);
      r2 += (od < dv || (od == dv && j < ln)) ? 1 : 0;
    }
    // redistribute rank->lane: lane r2 receives this lane's col
    myc = __builtin_amdgcn_ds_permute(r2 << 2, col);
  }
  if (ln < cK) {
    nbr[row * cK + ln] = myc;  // rank == lane
    atomicAdd(&cnt[bvert + myc], 1);
  }

  // fused v2e32: mean of h1 over this edge's 30 neighbors (quarter-wave)
  const unsigned* Xb = reinterpret_cast<const unsigned*>(h1 + bvert * cH);
  const int qg = ln >> 4, f2 = ln & 15;
  float s0 = 0.f, s1 = 0.f;
#pragma unroll
  for (int m = 0; m < 8; ++m) {
    int j = m * 4 + qg;
    int idx = __shfl(myc, j < cK ? j : 0);
    unsigned u = Xb[(size_t)idx * 16 + f2];
    bool ok = j < cK;
    s0 += ok ? bf16lo(u) : 0.f;
    s1 += ok ? bf16hi(u) : 0.f;
  }
  s0 += __shfl_xor(s0, 16);
  s1 += __shfl_xor(s1, 16);
  s0 += __shfl_xor(s0, 32);
  s1 += __shfl_xor(s1, 32);
  if (ln < 16) {
    BU cv;
    cv.b[0] = (__bf16)(s0 * (1.f / 30.f));
    cv.b[1] = (__bf16)(s1 * (1.f / 30.f));
    reinterpret_cast<unsigned*>(Y1)[row * 16 + f2] = cv.u;
  }
}

// ------- K3: CSR scan + fill merged (one 1024-thr block per sample) -------
// fill's dep on scan is sample-local -> scan, __syncthreads, fill. cur
// counters live in LDS (ds atomics), eliminating the global cur array.
__global__ __launch_bounds__(1024) void k_scanfill(
    const int* __restrict__ cnt, const int* __restrict__ nbr,
    int* __restrict__ rp, int* __restrict__ el) {
  __shared__ int curL[cL];  // 12.25 KB
  __shared__ int wsum[16];
  const int b = blockIdx.x;
  const int* c = cnt + b * cL;
  int* r = rp + b * (cL + 1);
  const int t = threadIdx.x;   // 0..1023
  const int ln = t & 63, w = t >> 6;  // 16 waves

  for (int n = t; n < cL; n += 1024) curL[n] = 0;

  // scan: each thread owns 4 contiguous elems [4t, 4t+4); 4096 >= 3136
  int v[4];
  int s = 0;
#pragma unroll
  for (int i = 0; i < 4; ++i) {
    int idx = 4 * t + i;
    v[i] = (idx < cL) ? c[idx] : 0;
    s += v[i];
  }
  int inc = s;
#pragma unroll
  for (int off = 1; off < 64; off <<= 1) {
    int u = __shfl_up(inc, off);
    if (ln >= off) inc += u;
  }
  if (ln == 63) wsum[w] = inc;
  __syncthreads();
  int carry = 0;
#pragma unroll
  for (int i = 0; i < 16; ++i) carry += (i < w) ? wsum[i] : 0;

  int excl = carry + inc - s;  // exclusive prefix of this thread's segment
#pragma unroll
  for (int i = 0; i < 4; ++i) {
    int idx = 4 * t + i;
    if (idx < cL) r[idx] = excl;
    excl += v[i];
  }
  if (t == 1023) r[cL] = excl;  // grand total (tail v[] are all zero)
  __syncthreads();  // rp + curL ready

  // fill: sample-local; LDS atomics for placement
  const int* nb = nbr + (size_t)b * cL * cK;
  int* elb = el + (size_t)b * cL * cK;
  for (int g = t; g < cL * cK; g += 1024) {
    int e = g / cK;
    int vtx = nb[g];
    vtx = min(max(vtx, 0), cL - 1);  // clamp: garbage-proof
    int p = r[vtx] + atomicAdd(&curL[vtx], 1);
    p = min(max(p, 0), cL * cK - 1);
    elb[p] = e;
  }
}

// ------- e2v(F=32) + relu + theta2 + bn fused (wave per vertex) -------
__global__ __launch_bounds__(256) void k_e2v_t2(const __bf16* __restrict__ Y,
                                                const int* __restrict__ rp,
                                                const int* __restrict__ el,
                                                const float* __restrict__ w2,
                                                const float* __restrict__ b2,
                                                const float* __restrict__ g2,
                                                const float* __restrict__ be2,
                                                __bf16* __restrict__ h2) {
  __shared__ float w2s[cH * cC];  // 8 KB
  {
    int t = threadIdx.x;
    for (int n = t; n < cH * cC; n += 256) w2s[n] = w2[n];
  }
  const int w  = threadIdx.x >> 6;
  const int ln = threadIdx.x & 63;
  const size_t vr = (size_t)blockIdx.x * 4 + w;  // b*cL + v
  const size_t b  = vr / cL;
  const int v = (int)(vr % cL);
  const int* rpb = rp + b * (cL + 1);
  const int s0 = rpb[v];
  const int deg = rpb[v + 1] - s0;  // >= 1 (self edge always selected)
  const int* elb = el + b * (size_t)cL * cK + s0;
  const __bf16* Yb = Y + b * cL * cH;
  const int hi = ln >> 5, f = ln & 31;
  float s = 0.f;

  for (int base = 0; base < deg; base += 64) {
    const int take = min(64, deg - base);
    const int eidx = elb[base + (ln < take ? ln : 0)];  // parallel load
    for (int j0 = 0; j0 < take; j0 += 16) {  // 8 independent per half
      float acc = 0.f;
#pragma unroll
      for (int k2 = 0; k2 < 8; ++k2) {
        int j = j0 + 2 * k2 + hi;
        int e0 = __shfl(eidx, j < take ? j : 0);
        float y = (float)Yb[(size_t)e0 * cH + f];
        acc += (j < take) ? y : 0.f;
      }
      s += acc;
    }
  }
  __syncthreads();  // w2s ready

  s += __shfl_xor(s, 32);
  float r = fmaxf(s / (float)deg, 0.f);  // e2v mean + relu

  float s2 = 0.f;
#pragma unroll 8
  for (int k = 0; k < cH; ++k) {
    float rk = __shfl(r, k);
    s2 = fmaf(rk, w2s[k * cC + ln], s2);
  }
  h2[vr * cC + ln] = (__bf16)((s2 + b2[ln]) * (g2[ln] * BN_SC) + be2[ln]);
}

// ------- v2e F=64 (wave/edge; uint-widened: 15 loads/lane, 2 bf16 each) ----
__global__ __launch_bounds__(256) void k_v2e64(const __bf16* __restrict__ X,
                                               const int* __restrict__ nbr,
                                               __bf16* __restrict__ Y) {
  const int w  = threadIdx.x >> 6;
  const int ln = threadIdx.x & 63;
  const size_t er = (size_t)blockIdx.x * 4 + w;  // b*cL + e
  const size_t b  = er / cL;
  const unsigned* Xb = reinterpret_cast<const unsigned*>(X + b * cL * cC);
  const int nb_l = nbr[er * cK + (ln < cK ? ln : cK - 1)];
  const int half = ln >> 5, f2 = ln & 31;  // uint f2 = features {2f2, 2f2+1}
  int idx[15];
#pragma unroll
  for (int m = 0; m < 15; ++m) idx[m] = __shfl(nb_l, 2 * m + half);
  unsigned v[15];
#pragma unroll
  for (int m = 0; m < 15; ++m) v[m] = Xb[(size_t)idx[m] * 32 + f2];
  float s0 = 0.f, s1 = 0.f;
#pragma unroll
  for (int m = 0; m < 15; ++m) {
    s0 += bf16lo(v[m]);
    s1 += bf16hi(v[m]);
  }
  s0 += __shfl_xor(s0, 32);
  s1 += __shfl_xor(s1, 32);
  if (half == 0) {
    BU cv;
    cv.b[0] = (__bf16)(s0 * (1.f / 30.f));
    cv.b[1] = (__bf16)(s1 * (1.f / 30.f));
    reinterpret_cast<unsigned*>(Y)[er * 32 + f2] = cv.u;
  }
}

// ------- final e2v (F=64, no relu), uint-widened gathers, fp32 out -------
__global__ __launch_bounds__(256) void k_e2v64(const __bf16* __restrict__ Y,
                                               const int* __restrict__ rp,
                                               const int* __restrict__ el,
                                               float* __restrict__ out) {
  const int w  = threadIdx.x >> 6;
  const int ln = threadIdx.x & 63;
  const size_t vr = (size_t)blockIdx.x * 4 + w;  // b*cL + v
  const size_t b  = vr / cL;
  const int v = (int)(vr % cL);
  const int* rpb = rp + b * (cL + 1);
  const int s0r = rpb[v];
  const int deg = rpb[v + 1] - s0r;
  const int* elb = el + b * (size_t)cL * cK + s0r;
  const unsigned* Yb = reinterpret_cast<const unsigned*>(Y + b * cL * cC);
  const int half = ln >> 5, f2 = ln & 31;
  float s0 = 0.f, s1 = 0.f;

  for (int base = 0; base < deg; base += 64) {
    const int take = min(64, deg - base);
    const int eidx = elb[base + (ln < take ? ln : 0)];
    for (int j0 = 0; j0 < take; j0 += 16) {  // 8 independent per half
      float a0 = 0.f, a1 = 0.f;
#pragma unroll
      for (int k2 = 0; k2 < 8; ++k2) {
        int j = j0 + 2 * k2 + half;
        int e0 = __shfl(eidx, j < take ? j : 0);
        unsigned u = Yb[(size_t)e0 * 32 + f2];
        bool ok = j < take;
        a0 += ok ? bf16lo(u) : 0.f;
        a1 += ok ? bf16hi(u) : 0.f;
      }
      s0 += a0;
      s1 += a1;
    }
  }
  s0 += __shfl_xor(s0, 32);
  s1 += __shfl_xor(s1, 32);
  // redistribute: feature ln lives on lane ln>>1, component ln&1
  float v0 = __shfl(s0, ln >> 1);
  float v1 = __shfl(s1, ln >> 1);
  out[vr * cC + ln] = ((ln & 1) ? v1 : v0) / (float)deg;
}

}  // namespace

extern "C" void kernel_launch(void* const* d_in, const int* in_sizes, int n_in,
                              void* d_out, int out_size, void* d_ws,
                              size_t ws_size, hipStream_t stream) {
  (void)in_sizes; (void)n_in; (void)out_size; (void)ws_size;
  const float* x   = (const float*)d_in[0];
  const float* w1  = (const float*)d_in[1];
  const float* b1  = (const float*)d_in[2];
  const float* g1  = (const float*)d_in[3];
  const float* be1 = (const float*)d_in[4];
  const float* w2  = (const float*)d_in[5];
  const float* b2  = (const float*)d_in[6];
  const float* g2  = (const float*)d_in[7];
  const float* be2 = (const float*)d_in[8];
  float* out = (float*)d_out;

  // workspace: ~27.5 MB peak (<= proven ~31.5 MB)
  char* base = (char*)d_ws;
  size_t off = 0;
  auto carve = [&](size_t bytes) {
    char* p = base + off;
    off += (bytes + 255) & ~(size_t)255;
    return p;
  };
  float* sqf = (float*)carve((size_t)NV * 4);
  int*   nbr = (int*)carve((size_t)NV * cK * 4);
  int*   rp  = (int*)carve((size_t)cB * (cL + 1) * 4);
  int*   cnt = (int*)carve((size_t)NV * 4);
  // region A: {xhi|xlo} (dead after k_sweep) then {el}
  char* RA = carve((size_t)NV * 64 * 2 * 2);  // 6,422,528
  ushort* xhi = (ushort*)RA;
  ushort* xlo = (ushort*)(RA + 3211264);
  int* el = (int*)RA;
  // region C: candq [0, 8028160) live until rescore ends; h1/Y1 placed
  // AFTER it (fused rescore reads candq while writing Y1); h2/Y2 follow.
  char* RC = carve(17661952);
  unsigned* candq = (unsigned*)RC;                 // 8,028,160 B
  __bf16* h1 = (__bf16*)(RC + 8028160);            // 1.6 MB
  __bf16* Y1 = (__bf16*)(RC + 9633792);            // 1.6 MB
  __bf16* h2 = (__bf16*)(RC + 11239424);           // 3.2 MB
  __bf16* Y2 = (__bf16*)(RC + 14450688);           // 3.2 MB

  k_splitth<<<NV / 8, 256, 0, stream>>>(x, w1, b1, g1, be1, xhi, xlo, sqf,
                                        cnt, h1);
  k_sweep<<<dim3(98, 2, cB), 128, 0, stream>>>(xhi, xlo, sqf, candq);
  k_rescore<<<NV / 4, 256, 0, stream>>>(x, candq, h1, nbr, cnt, Y1);

  k_scanfill<<<cB, 1024, 0, stream>>>(cnt, nbr, rp, el);

  k_e2v_t2<<<NV / 4, 256, 0, stream>>>(Y1, rp, el, w2, b2, g2, be2, h2);
  k_v2e64<<<NV / 4, 256, 0, stream>>>(h2, nbr, Y2);
  k_e2v64<<<NV / 4, 256, 0, stream>>>(Y2, rp, el, out);
}

// Round 10
// 371.549 us; speedup vs baseline: 2.3744x; 1.2033x over previous
//
#include <hip/hip_runtime.h>
#include <math.h>

// HGNNPBlock: per-sample kNN hypergraph (k=30) + 2x (theta -> bn -> v2v mean).
// B=8, L=56*56=3136, C=64, hid=32.
//
// R23 = R19 (373.5us, best) reverted from R22's failed scanfill merge
// (127us at 8 blocks: fill needs grid-wide parallelism; merges must
// preserve the widest phase's parallelism) + two chain cuts:
//  (1) k_scan writes cur[v] = rp[v]; k_fill drops its rp load ->
//      753K dependent chains lose one L2 round-trip each.
//  (2) k_splitth: 32 verts/block (grid 784) -> w1 staging traffic /4.
// R22 measurement banked: R19 scan+fill+boundary ~= 53us (fill ~35-40,
// second-largest item after sweep 121.5).

namespace {

constexpr int cB = 8;
constexpr int cL = 3136;
constexpr int cC = 64;
constexpr int cH = 32;
constexpr int cK = 30;
constexpr int NV = cB * cL;   // 25088
constexpr int QD = 10;        // per-lane queue depth
constexpr float BN_SC = 0.99999500003749964f;  // 1/sqrt(1+1e-5) in fp32

typedef __bf16 bf16x8 __attribute__((ext_vector_type(8)));
typedef float floatx4 __attribute__((ext_vector_type(4)));

union BU {
  __bf16 b[2];
  unsigned u;
};

__device__ inline unsigned umin2(unsigned a, unsigned b) { return a < b ? a : b; }
__device__ inline unsigned umax2(unsigned a, unsigned b) { return a > b ? a : b; }
__device__ inline unsigned umin3(unsigned a, unsigned b, unsigned c) {
  return umin2(umin2(a, b), c);  // compiler fuses to v_min3_u32
}
__device__ inline float bf16lo(unsigned u) { return __uint_as_float(u << 16); }
__device__ inline float bf16hi(unsigned u) {
  return __uint_as_float(u & 0xFFFF0000u);
}

// sort a bitonic 64-sequence (one value per lane) ascending, shfl-only
__device__ inline unsigned bclean64(unsigned v, int ln) {
#pragma unroll
  for (int off = 32; off; off >>= 1) {
    unsigned p = (unsigned)__shfl_xor((int)v, off);
    v = (ln & off) ? umax2(v, p) : umin2(v, p);
  }
  return v;
}

// ------- K0: split + |x|^2 + theta1 + bn, fused (per-vertex maps over x) ---
// grid 784 x 256: block = 32 vertices (4 chunks of 8) x 32 features.
__global__ __launch_bounds__(256) void k_splitth(
    const float* __restrict__ x, const float* __restrict__ w1,
    const float* __restrict__ b1, const float* __restrict__ g1,
    const float* __restrict__ be1, ushort* __restrict__ xhi,
    ushort* __restrict__ xlo, float* __restrict__ sqf,
    int* __restrict__ cnt, __bf16* __restrict__ h1) {
  __shared__ float w1s[cC * cH];  // 8 KB
  __shared__ float xs[32 * 64];   // 8 KB
  const int t = threadIdx.x;
  const int v0 = blockIdx.x * 32;
  for (int n = t; n < cC * cH; n += 256) w1s[n] = w1[n];
#pragma unroll
  for (int c = 0; c < 4; ++c) {
    const int vv = v0 + c * 8;
    float2 xv = reinterpret_cast<const float2*>(x + (size_t)vv * 64)[t];
    xs[c * 512 + 2 * t] = xv.x;
    xs[c * 512 + 2 * t + 1] = xv.y;
    BU hh, ll;
    hh.b[0] = (__bf16)xv.x;
    hh.b[1] = (__bf16)xv.y;
    ll.b[0] = (__bf16)(xv.x - (float)hh.b[0]);
    ll.b[1] = (__bf16)(xv.y - (float)hh.b[1]);
    reinterpret_cast<unsigned*>(xhi)[(size_t)vv * 32 + t] = hh.u;
    reinterpret_cast<unsigned*>(xlo)[(size_t)vv * 32 + t] = ll.u;
    float ss = xv.x * xv.x + xv.y * xv.y;  // row r=t>>5 spans lanes r*32..+31
#pragma unroll
    for (int off = 1; off < 32; off <<= 1) ss += __shfl_xor(ss, off);
    if ((t & 31) == 0) sqf[vv + (t >> 5)] = ss * 1024.f + 262144.f;  // q20
  }
  if (t < 32) cnt[v0 + t] = 0;
  __syncthreads();
  const int r = t >> 5, f = t & 31;
#pragma unroll
  for (int c = 0; c < 4; ++c) {
    float s = 0.f;
#pragma unroll
    for (int k = 0; k < cC; ++k)
      s = fmaf(xs[(c * 8 + r) * 64 + k], w1s[k * cH + f], s);
    h1[(size_t)(v0 + c * 8 + r) * cH + f] =
        (__bf16)((s + b1[f]) * (g1[f] * BN_SC) + be1[f]);
  }
}

// ------- K1: fused gram sweep + branchless top-10 -> per-half top-40 ------
// grid (98, 2, 8): 32-row strip x col-half x sample. block 128 (2 waves);
// wave w rows w*16..w*16+15; lane (tx,qd) rows qd*4+e, cols f*16+tx (f<2).
__global__ __launch_bounds__(128, 4) void k_sweep(
    const ushort* __restrict__ xhi, const ushort* __restrict__ xlo,
    const float* __restrict__ sqf, unsigned* __restrict__ candq) {
  const int ib = blockIdx.x, qt = blockIdx.y, b = blockIdx.z;
  const int r0 = ib * 32;
  const int jb0 = qt * 1568;
  const int ntile = 49;  // 32-col tiles; 2 * 49*32 = 3136 (exact halves)
  const size_t bbase = (size_t)b * cL;

  __shared__ ushort aHi[32 * 72], aLo[32 * 72];  // stride 72: conflict-free
  __shared__ ushort bHi[32 * 72], bLo[32 * 72];
  __shared__ float sqJs[32];

  const int t  = threadIdx.x;  // 0..127
  const int ln = t & 63;
  const int w  = t >> 6;       // wave -> 16-row group
  const int tx = ln & 15;
  const int qd = ln >> 4;

#pragma unroll
  for (int it = 0; it < 2; ++it) {  // stage A strip (32 rows x 8 uint4 chunks)
    int idx = t + 128 * it;
    int r = idx >> 3, blk = idx & 7;
    *reinterpret_cast<uint4*>(&aHi[r * 72 + blk * 8]) =
        *reinterpret_cast<const uint4*>(&xhi[(bbase + r0 + r) * 64 + blk * 8]);
    *reinterpret_cast<uint4*>(&aLo[r * 72 + blk * 8]) =
        *reinterpret_cast<const uint4*>(&xlo[(bbase + r0 + r) * 64 + blk * 8]);
  }
  __syncthreads();

  bf16x8 aH[2], aL[2];
#pragma unroll
  for (int kk = 0; kk < 2; ++kk) {
    aH[kk] = *reinterpret_cast<const bf16x8*>(
        &aHi[(w * 16 + tx) * 72 + kk * 32 + qd * 8]);
    aL[kk] = *reinterpret_cast<const bf16x8*>(
        &aLo[(w * 16 + tx) * 72 + kk * 32 + qd * 8]);
  }

  unsigned q[4][QD];  // per-row sorted top-QD (ascending), packed q20|col12
#pragma unroll
  for (int e = 0; e < 4; ++e)
#pragma unroll
    for (int k = 0; k < QD; ++k) q[e][k] = 0xFFFFFFFFu;

  // register prefetch of B tiles (async-STAGE split)
  const int pr  = (t + 0)   >> 3, pblk  = (t + 0)   & 7;   // it=0 slot
  const int pr1 = (t + 128) >> 3, pblk1 = (t + 128) & 7;   // it=1 slot
  uint4 pH0, pH1, pL0, pL1;
  float pS = 0.f;
  {
    const int jb = jb0;
    pH0 = *reinterpret_cast<const uint4*>(&xhi[(bbase + jb + pr) * 64 + pblk * 8]);
    pL0 = *reinterpret_cast<const uint4*>(&xlo[(bbase + jb + pr) * 64 + pblk * 8]);
    pH1 = *reinterpret_cast<const uint4*>(&xhi[(bbase + jb + pr1) * 64 + pblk1 * 8]);
    pL1 = *reinterpret_cast<const uint4*>(&xlo[(bbase + jb + pr1) * 64 + pblk1 * 8]);
    if (t < 32) pS = sqf[bbase + jb + t];
  }

  for (int st = 0; st < ntile; ++st) {
    __syncthreads();  // prev compute done -> LDS writable; drains prefetch vmcnt
    *reinterpret_cast<uint4*>(&bHi[pr * 72 + pblk * 8])   = pH0;
    *reinterpret_cast<uint4*>(&bLo[pr * 72 + pblk * 8])   = pL0;
    *reinterpret_cast<uint4*>(&bHi[pr1 * 72 + pblk1 * 8]) = pH1;
    *reinterpret_cast<uint4*>(&bLo[pr1 * 72 + pblk1 * 8]) = pL1;
    if (t < 32) sqJs[t] = pS;
    __syncthreads();  // tile st ready

    // issue loads for tile st+1 NOW (after the barrier so its vmcnt(0) drain
    // doesn't eat them); they retire during the compute below.
    if (st + 1 < ntile) {
      const int jb = jb0 + (st + 1) * 32;
      pH0 = *reinterpret_cast<const uint4*>(&xhi[(bbase + jb + pr) * 64 + pblk * 8]);
      pL0 = *reinterpret_cast<const uint4*>(&xlo[(bbase + jb + pr) * 64 + pblk * 8]);
      pH1 = *reinterpret_cast<const uint4*>(&xhi[(bbase + jb + pr1) * 64 + pblk1 * 8]);
      pL1 = *reinterpret_cast<const uint4*>(&xlo[(bbase + jb + pr1) * 64 + pblk1 * 8]);
      if (t < 32) pS = sqf[bbase + jb + t];
    }
    __builtin_amdgcn_sched_barrier(0);  // keep prefetch issue above compute

    unsigned pk[2][4];  // packed candidates per f per e
#pragma unroll
    for (int f = 0; f < 2; ++f) {
      const int bro = (f * 16 + tx) * 72 + qd * 8;
      bf16x8 bh0 = *reinterpret_cast<const bf16x8*>(&bHi[bro]);
      bf16x8 bh1 = *reinterpret_cast<const bf16x8*>(&bHi[bro + 32]);
      bf16x8 bl0 = *reinterpret_cast<const bf16x8*>(&bLo[bro]);
      bf16x8 bl1 = *reinterpret_cast<const bf16x8*>(&bLo[bro + 32]);
      floatx4 acc = {0.f, 0.f, 0.f, 0.f};
      acc = __builtin_amdgcn_mfma_f32_16x16x32_bf16(aH[0], bh0, acc, 0, 0, 0);
      acc = __builtin_amdgcn_mfma_f32_16x16x32_bf16(aH[1], bh1, acc, 0, 0, 0);
      acc = __builtin_amdgcn_mfma_f32_16x16x32_bf16(aH[0], bl0, acc, 0, 0, 0);
      acc = __builtin_amdgcn_mfma_f32_16x16x32_bf16(aH[1], bl1, acc, 0, 0, 0);
      acc = __builtin_amdgcn_mfma_f32_16x16x32_bf16(aL[0], bh0, acc, 0, 0, 0);
      acc = __builtin_amdgcn_mfma_f32_16x16x32_bf16(aL[1], bh1, acc, 0, 0, 0);
      const float sjs = sqJs[f * 16 + tx];
      const unsigned col = (unsigned)(jb0 + st * 32 + f * 16 + tx);
#pragma unroll
      for (int e = 0; e < 4; ++e) {
        // q20 quantized d2 (|xi|^2 dropped: row-constant, ranks unaffected)
        float qf = fmaf(acc[e], -2048.f, sjs);
        qf = fminf(fmaxf(qf, 0.f), 1048575.f);  // clamp to 20 bits
        pk[f][e] = ((unsigned)qf << 12) | col;
      }
    }

    // branchless pair-insert: keep smallest QD of q U {a0,a1}, a0<=a1.
    // new_q[i] = min3(q[i], max(q[i-1],a0), max(q[i-2],a1)), descending i.
#pragma unroll
    for (int e = 0; e < 4; ++e) {
      unsigned a0 = umin2(pk[0][e], pk[1][e]);
      unsigned a1 = umax2(pk[0][e], pk[1][e]);
#pragma unroll
      for (int i = QD - 1; i >= 2; --i)
        q[e][i] = umin3(q[e][i], umax2(q[e][i - 1], a0),
                        umax2(q[e][i - 2], a1));
      q[e][1] = umin3(q[e][1], umax2(q[e][0], a0), a1);
      q[e][0] = umin3(q[e][0], a0, a1);
    }
  }

  // extraction: 40 wave-min pops per row; e-interleaved -> 4 independent
  // dependency chains in flight.
  unsigned* cr[4];
#pragma unroll
  for (int e = 0; e < 4; ++e)
    cr[e] = candq + (bbase + r0 + w * 16 + qd * 4 + e) * 80 + qt * 40;
  for (int it = 0; it < 40; ++it) {
    unsigned h0 = q[0][0], h1 = q[1][0], h2 = q[2][0], h3 = q[3][0];
    unsigned m0 = h0, m1 = h1, m2 = h2, m3 = h3;
#pragma unroll
    for (int off = 1; off < 16; off <<= 1) {
      m0 = umin2(m0, (unsigned)__shfl_xor((int)m0, off));
      m1 = umin2(m1, (unsigned)__shfl_xor((int)m1, off));
      m2 = umin2(m2, (unsigned)__shfl_xor((int)m2, off));
      m3 = umin2(m3, (unsigned)__shfl_xor((int)m3, off));
    }
    if (tx == 0) {
      cr[0][it] = m0;
      cr[1][it] = m1;
      cr[2][it] = m2;
      cr[3][it] = m3;
    }
    if (h0 == m0) {  // keys distinct (col in low bits) -> exactly one pop
#pragma unroll
      for (int k = 0; k < QD - 1; ++k) q[0][k] = q[0][k + 1];
      q[0][QD - 1] = 0xFFFFFFFFu;
    }
    if (h1 == m1) {
#pragma unroll
      for (int k = 0; k < QD - 1; ++k) q[1][k] = q[1][k + 1];
      q[1][QD - 1] = 0xFFFFFFFFu;
    }
    if (h2 == m2) {
#pragma unroll
      for (int k = 0; k < QD - 1; ++k) q[2][k] = q[2][k + 1];
      q[2][QD - 1] = 0xFFFFFFFFu;
    }
    if (h3 == m3) {
#pragma unroll
      for (int k = 0; k < QD - 1; ++k) q[3][k] = q[3][k + 1];
      q[3][QD - 1] = 0xFFFFFFFFu;
    }
  }
}

// ------- K2: merge 2 sorted lists + cond. fp64 re-rank + fused v2e32 ------
__global__ __launch_bounds__(256) void k_rescore(
    const float* __restrict__ x, const unsigned* __restrict__ candq,
    const __bf16* __restrict__ h1, int* __restrict__ nbr,
    int* __restrict__ cnt, __bf16* __restrict__ Y1) {
  const int w  = threadIdx.x >> 6;
  const int ln = threadIdx.x & 63;
  const size_t row = (size_t)blockIdx.x * 4 + w;
  const size_t bvert = row - (row % cL);  // b*cL

  const unsigned* cq = candq + row * 80;
  unsigned A = (ln < 40) ? cq[ln]      : 0xFFFFFFFFu;
  unsigned B = (ln < 40) ? cq[40 + ln] : 0xFFFFFFFFu;

  // split-min + bitonic clean: sorted lower-64 of the 2-list union
  unsigned g = umin2(A, (unsigned)__shfl((int)B, 63 - ln));
  g = bclean64(g, ln);  // sorted asc; lanes 0..39 = global top-40 (all real)

  const unsigned qv = g >> 12;  // 20-bit quantized distance
  const int col = min((int)(g & 0xFFFu), cL - 1);  // clamp: garbage-proof

  // quantized gap at the 29/30 boundary (sorted -> just neighbors)
  unsigned q29 = (unsigned)__shfl((int)qv, 29);
  unsigned q30 = (unsigned)__shfl((int)qv, 30);
  int myc = col;  // fast path: lane == rank already
  if (!(q30 > q29 + 6)) {  // wave-uniform branch
    // ambiguous boundary: exact fp64 re-rank of the 40 merged candidates
    float4 xi[16];
    const float4* xi4 = reinterpret_cast<const float4*>(x + row * 64);
#pragma unroll
    for (int c = 0; c < 16; ++c) xi[c] = xi4[c];
    double dv = 1e300;
    if (ln < 40) {
      const float4* xj4 =
          reinterpret_cast<const float4*>(x + (bvert + col) * 64);
      double ax = 0.0, ay = 0.0, az = 0.0, aw = 0.0;
#pragma unroll
      for (int c = 0; c < 16; ++c) {
        float4 xj = xj4[c];
        double d0 = (double)xi[c].x - (double)xj.x; ax = fma(d0, d0, ax);
        double d1 = (double)xi[c].y - (double)xj.y; ay = fma(d1, d1, ay);
        double d2 = (double)xi[c].z - (double)xj.z; az = fma(d2, d2, az);
        double d3 = (double)xi[c].w - (double)xj.w; aw = fma(d3, d3, aw);
      }
      dv = (ax + ay) + (az + aw);
    }
    int r2 = 0;
    for (int j = 0; j < 40; ++j) {
      double od = __shfl(dv, j);
      r2 += (od < dv || (od == dv && j < ln)) ? 1 : 0;
    }
    // redistribute rank->lane: lane r2 receives this lane's col
    myc = __builtin_amdgcn_ds_permute(r2 << 2, col);
  }
  if (ln < cK) {
    nbr[row * cK + ln] = myc;  // rank == lane
    atomicAdd(&cnt[bvert + myc], 1);
  }

  // fused v2e32: mean of h1 over this edge's 30 neighbors (quarter-wave)
  const unsigned* Xb = reinterpret_cast<const unsigned*>(h1 + bvert * cH);
  const int qg = ln >> 4, f2 = ln & 15;
  float s0 = 0.f, s1 = 0.f;
#pragma unroll
  for (int m = 0; m < 8; ++m) {
    int j = m * 4 + qg;
    int idx = __shfl(myc, j < cK ? j : 0);
    unsigned u = Xb[(size_t)idx * 16 + f2];
    bool ok = j < cK;
    s0 += ok ? bf16lo(u) : 0.f;
    s1 += ok ? bf16hi(u) : 0.f;
  }
  s0 += __shfl_xor(s0, 16);
  s1 += __shfl_xor(s1, 16);
  s0 += __shfl_xor(s0, 32);
  s1 += __shfl_xor(s1, 32);
  if (ln < 16) {
    BU cv;
    cv.b[0] = (__bf16)(s0 * (1.f / 30.f));
    cv.b[1] = (__bf16)(s1 * (1.f / 30.f));
    reinterpret_cast<unsigned*>(Y1)[row * 16 + f2] = cv.u;
  }
}

// ------- CSR: scan (also seeds cur = rp) + fill -------
__global__ __launch_bounds__(1024) void k_scan(const int* __restrict__ cnt,
                                               int* __restrict__ rp,
                                               int* __restrict__ cur) {
  const int b = blockIdx.x;
  const int* c = cnt + b * cL;
  int* r = rp + b * (cL + 1);
  int* cu = cur + b * cL;
  const int t = threadIdx.x;   // 0..1023
  const int ln = t & 63, w = t >> 6;  // 16 waves

  int v[4];
  int s = 0;
#pragma unroll
  for (int i = 0; i < 4; ++i) {
    int idx = 4 * t + i;
    v[i] = (idx < cL) ? c[idx] : 0;
    s += v[i];
  }
  int inc = s;
#pragma unroll
  for (int off = 1; off < 64; off <<= 1) {
    int u = __shfl_up(inc, off);
    if (ln >= off) inc += u;
  }
  __shared__ int wsum[16];
  if (ln == 63) wsum[w] = inc;
  __syncthreads();
  int carry = 0;
#pragma unroll
  for (int i = 0; i < 16; ++i) carry += (i < w) ? wsum[i] : 0;

  int excl = carry + inc - s;  // exclusive prefix of this thread's segment
#pragma unroll
  for (int i = 0; i < 4; ++i) {
    int idx = 4 * t + i;
    if (idx < cL) {
      r[idx] = excl;
      cu[idx] = excl;  // seed fill's counter with the CSR base
    }
    excl += v[i];
  }
  if (t == 1023) r[cL] = excl;  // grand total (tail v[] are all zero)
}

// cur pre-seeded with rp -> single atomic, no rp load in the chain
__global__ void k_fill(const int* __restrict__ nbr, int* __restrict__ cur,
                       int* __restrict__ el) {
  int g = blockIdx.x * 256 + threadIdx.x;
  if (g >= NV * cK) return;
  int b = g / (cL * cK);
  int e = (g / cK) % cL;
  int v = nbr[g];
  v = min(max(v, 0), cL - 1);  // clamp: garbage cannot become a wild write
  int p = atomicAdd(&cur[b * cL + v], 1);
  p = min(max(p, 0), cL * cK - 1);
  el[(size_t)b * cL * cK + p] = e;
}

// ------- e2v(F=32) + relu + theta2 + bn fused (wave per vertex) -------
__global__ __launch_bounds__(256) void k_e2v_t2(const __bf16* __restrict__ Y,
                                                const int* __restrict__ rp,
                                                const int* __restrict__ el,
                                                const float* __restrict__ w2,
                                                const float* __restrict__ b2,
                                                const float* __restrict__ g2,
                                                const float* __restrict__ be2,
                                                __bf16* __restrict__ h2) {
  __shared__ float w2s[cH * cC];  // 8 KB
  {
    int t = threadIdx.x;
    for (int n = t; n < cH * cC; n += 256) w2s[n] = w2[n];
  }
  const int w  = threadIdx.x >> 6;
  const int ln = threadIdx.x & 63;
  const size_t vr = (size_t)blockIdx.x * 4 + w;  // b*cL + v
  const size_t b  = vr / cL;
  const int v = (int)(vr % cL);
  const int* rpb = rp + b * (cL + 1);
  const int s0 = rpb[v];
  const int deg = rpb[v + 1] - s0;  // >= 1 (self edge always selected)
  const int* elb = el + b * (size_t)cL * cK + s0;
  const __bf16* Yb = Y + b * cL * cH;
  const int hi = ln >> 5, f = ln & 31;
  float s = 0.f;

  for (int base = 0; base < deg; base += 64) {
    const int take = min(64, deg - base);
    const int eidx = elb[base + (ln < take ? ln : 0)];  // parallel load
    for (int j0 = 0; j0 < take; j0 += 16) {  // 8 independent per half
      float acc = 0.f;
#pragma unroll
      for (int k2 = 0; k2 < 8; ++k2) {
        int j = j0 + 2 * k2 + hi;
        int e0 = __shfl(eidx, j < take ? j : 0);
        float y = (float)Yb[(size_t)e0 * cH + f];
        acc += (j < take) ? y : 0.f;
      }
      s += acc;
    }
  }
  __syncthreads();  // w2s ready

  s += __shfl_xor(s, 32);
  float r = fmaxf(s / (float)deg, 0.f);  // e2v mean + relu

  float s2 = 0.f;
#pragma unroll 8
  for (int k = 0; k < cH; ++k) {
    float rk = __shfl(r, k);
    s2 = fmaf(rk, w2s[k * cC + ln], s2);
  }
  h2[vr * cC + ln] = (__bf16)((s2 + b2[ln]) * (g2[ln] * BN_SC) + be2[ln]);
}

// ------- v2e F=64 (wave/edge; uint-widened: 15 loads/lane, 2 bf16 each) ----
__global__ __launch_bounds__(256) void k_v2e64(const __bf16* __restrict__ X,
                                               const int* __restrict__ nbr,
                                               __bf16* __restrict__ Y) {
  const int w  = threadIdx.x >> 6;
  const int ln = threadIdx.x & 63;
  const size_t er = (size_t)blockIdx.x * 4 + w;  // b*cL + e
  const size_t b  = er / cL;
  const unsigned* Xb = reinterpret_cast<const unsigned*>(X + b * cL * cC);
  const int nb_l = nbr[er * cK + (ln < cK ? ln : cK - 1)];
  const int half = ln >> 5, f2 = ln & 31;  // uint f2 = features {2f2, 2f2+1}
  int idx[15];
#pragma unroll
  for (int m = 0; m < 15; ++m) idx[m] = __shfl(nb_l, 2 * m + half);
  unsigned v[15];
#pragma unroll
  for (int m = 0; m < 15; ++m) v[m] = Xb[(size_t)idx[m] * 32 + f2];
  float s0 = 0.f, s1 = 0.f;
#pragma unroll
  for (int m = 0; m < 15; ++m) {
    s0 += bf16lo(v[m]);
    s1 += bf16hi(v[m]);
  }
  s0 += __shfl_xor(s0, 32);
  s1 += __shfl_xor(s1, 32);
  if (half == 0) {
    BU cv;
    cv.b[0] = (__bf16)(s0 * (1.f / 30.f));
    cv.b[1] = (__bf16)(s1 * (1.f / 30.f));
    reinterpret_cast<unsigned*>(Y)[er * 32 + f2] = cv.u;
  }
}

// ------- final e2v (F=64, no relu), uint-widened gathers, fp32 out -------
__global__ __launch_bounds__(256) void k_e2v64(const __bf16* __restrict__ Y,
                                               const int* __restrict__ rp,
                                               const int* __restrict__ el,
                                               float* __restrict__ out) {
  const int w  = threadIdx.x >> 6;
  const int ln = threadIdx.x & 63;
  const size_t vr = (size_t)blockIdx.x * 4 + w;  // b*cL + v
  const size_t b  = vr / cL;
  const int v = (int)(vr % cL);
  const int* rpb = rp + b * (cL + 1);
  const int s0r = rpb[v];
  const int deg = rpb[v + 1] - s0r;
  const int* elb = el + b * (size_t)cL * cK + s0r;
  const unsigned* Yb = reinterpret_cast<const unsigned*>(Y + b * cL * cC);
  const int half = ln >> 5, f2 = ln & 31;
  float s0 = 0.f, s1 = 0.f;

  for (int base = 0; base < deg; base += 64) {
    const int take = min(64, deg - base);
    const int eidx = elb[base + (ln < take ? ln : 0)];
    for (int j0 = 0; j0 < take; j0 += 16) {  // 8 independent per half
      float a0 = 0.f, a1 = 0.f;
#pragma unroll
      for (int k2 = 0; k2 < 8; ++k2) {
        int j = j0 + 2 * k2 + half;
        int e0 = __shfl(eidx, j < take ? j : 0);
        unsigned u = Yb[(size_t)e0 * 32 + f2];
        bool ok = j < take;
        a0 += ok ? bf16lo(u) : 0.f;
        a1 += ok ? bf16hi(u) : 0.f;
      }
      s0 += a0;
      s1 += a1;
    }
  }
  s0 += __shfl_xor(s0, 32);
  s1 += __shfl_xor(s1, 32);
  // redistribute: feature ln lives on lane ln>>1, component ln&1
  float v0 = __shfl(s0, ln >> 1);
  float v1 = __shfl(s1, ln >> 1);
  out[vr * cC + ln] = ((ln & 1) ? v1 : v0) / (float)deg;
}

}  // namespace

extern "C" void kernel_launch(void* const* d_in, const int* in_sizes, int n_in,
                              void* d_out, int out_size, void* d_ws,
                              size_t ws_size, hipStream_t stream) {
  (void)in_sizes; (void)n_in; (void)out_size; (void)ws_size;
  const float* x   = (const float*)d_in[0];
  const float* w1  = (const float*)d_in[1];
  const float* b1  = (const float*)d_in[2];
  const float* g1  = (const float*)d_in[3];
  const float* be1 = (const float*)d_in[4];
  const float* w2  = (const float*)d_in[5];
  const float* b2  = (const float*)d_in[6];
  const float* g2  = (const float*)d_in[7];
  const float* be2 = (const float*)d_in[8];
  float* out = (float*)d_out;

  // workspace: ~27.5 MB peak (<= proven ~31.5 MB)
  char* base = (char*)d_ws;
  size_t off = 0;
  auto carve = [&](size_t bytes) {
    char* p = base + off;
    off += (bytes + 255) & ~(size_t)255;
    return p;
  };
  float* sqf = (float*)carve((size_t)NV * 4);
  int*   nbr = (int*)carve((size_t)NV * cK * 4);
  int*   rp  = (int*)carve((size_t)cB * (cL + 1) * 4);
  int*   cnt = (int*)carve((size_t)NV * 4);
  int*   cur = (int*)carve((size_t)NV * 4);
  // region A: {xhi|xlo} (dead after k_sweep) then {el}
  char* RA = carve((size_t)NV * 64 * 2 * 2);  // 6,422,528
  ushort* xhi = (ushort*)RA;
  ushort* xlo = (ushort*)(RA + 3211264);
  int* el = (int*)RA;
  // region C: candq [0, 8028160) live until rescore ends; h1/Y1 placed
  // AFTER it (fused rescore reads candq while writing Y1); h2/Y2 follow.
  char* RC = carve(17661952);
  unsigned* candq = (unsigned*)RC;                 // 8,028,160 B
  __bf16* h1 = (__bf16*)(RC + 8028160);            // 1.6 MB
  __bf16* Y1 = (__bf16*)(RC + 9633792);            // 1.6 MB
  __bf16* h2 = (__bf16*)(RC + 11239424);           // 3.2 MB
  __bf16* Y2 = (__bf16*)(RC + 14450688);           // 3.2 MB

  k_splitth<<<NV / 32, 256, 0, stream>>>(x, w1, b1, g1, be1, xhi, xlo, sqf,
                                         cnt, h1);
  k_sweep<<<dim3(98, 2, cB), 128, 0, stream>>>(xhi, xlo, sqf, candq);
  k_rescore<<<NV / 4, 256, 0, stream>>>(x, candq, h1, nbr, cnt, Y1);

  k_scan<<<cB, 1024, 0, stream>>>(cnt, rp, cur);
  k_fill<<<(NV * cK) / 256, 256, 0, stream>>>(nbr, cur, el);

  k_e2v_t2<<<NV / 4, 256, 0, stream>>>(Y1, rp, el, w2, b2, g2, be2, h2);
  k_v2e64<<<NV / 4, 256, 0, stream>>>(h2, nbr, Y2);
  k_e2v64<<<NV / 4, 256, 0, stream>>>(Y2, rp, el, out);
}